// Round 2
// baseline (823.247 us; speedup 1.0000x reference)
//
#include <hip/hip_runtime.h>

typedef float floatx4 __attribute__((ext_vector_type(4)));
typedef __bf16 bf16x8 __attribute__((ext_vector_type(8)));

#define D0_ 19
#define H0_ 200
#define W0_ 176
#define HW_ (H0_*W0_)          // 35200
#define NCELL0 (D0_*HW_)       // 668800
#define D1_ 9
#define NCELL1 (D1_*HW_)       // 316800
#define D2_ 4
#define NCELL2 (D2_*HW_)       // 140800
#define NV_ 40000
#define CAP0 40000
#define CAP1 80000
#define CAP2 140800
#define EPS_ 1e-3f

__device__ __forceinline__ float bf2f(short s){
    union { unsigned u; float f; } x; x.u = ((unsigned)(unsigned short)s) << 16; return x.f;
}
__device__ __forceinline__ short f2bf(float f){
    union { float f; unsigned u; } x; x.f = f;
    unsigned r = x.u + 0x7fffu + ((x.u >> 16) & 1u);
    return (short)(r >> 16);
}

// ---------------- zero ----------------
__global__ void k_zero(int4* p, long n){
    long i = (long)blockIdx.x * blockDim.x + threadIdx.x;
    long st = (long)gridDim.x * blockDim.x;
    int4 z = {0,0,0,0};
    for (; i < n; i += st) p[i] = z;
}

// ---------------- BN constants (fp32 in): scale = g*rsqrt(v+eps), shift = b - m*scale ----------------
__global__ void k_bnprep(const float* g, const float* b, const float* m, const float* v,
                         float* scale, float* shift){
    int i = blockIdx.x * 256 + threadIdx.x;
    if (i < 5*64){
        float s = g[i] / sqrtf(v[i] + EPS_);
        scale[i] = s;
        shift[i] = b[i] - m[i] * s;
    }
}

// ---------------- repack fp32 weights -> bf16 MFMA B-fragment order ----------------
// GEMM K-index: k = j*128 + ci (j = spatial tap, ci = 128 A-channels; for 64-ch
// layers ci is hi/lo duplicated -> src channel ci&63).
// dest: Bout[ ((kchunk*4 + ntile)*64 + lane)*8 + jj ],  lane = ((k>>3)&3)*16 + (n&15)
__global__ void k_repack(const float* w, short* Bout, int K, int KCsrc, int NSP){
    int i = blockIdx.x * 256 + threadIdx.x;
    if (i >= K * 64) return;
    int k = i >> 6, n = i & 63;
    int j = k >> 7;
    int ci = k & 127;
    int cis = (KCsrc == 128) ? ci : (ci & 63);
    short val = f2bf(w[(n * KCsrc + cis) * NSP + j]);   // exact: weights are bf16-rounded
    int kc = k >> 5, lanehi = (k >> 3) & 3, jj = k & 7;
    int nt = n >> 4, lane = lanehi * 16 + (n & 15);
    Bout[((kc * 4 + nt) * 64 + lane) * 8 + jj] = val;
}

// ---------------- mark occupied cells ----------------
__global__ void k_mark(const int* coors, int* idx0){
    int v = blockIdx.x * 256 + threadIdx.x;
    if (v >= NV_) return;
    int z = coors[v*4+1], y = coors[v*4+2], x = coors[v*4+3];
    idx0[(z*H0_ + y)*W0_ + x] = 1;   // racing identical stores: benign
}

// ---------------- compact level 0 (idx0: 1 -> row id, 0 -> -1) ----------------
__global__ void k_compact0(int* idx0, int* list0, int* cnt0){
    int c = blockIdx.x * 256 + threadIdx.x;
    if (c >= NCELL0) return;
    if (idx0[c] > 0){
        int r = atomicAdd(cnt0, 1);
        idx0[c] = r;
        int z = c / HW_; int rem = c - z * HW_;
        int y = rem / W0_; int x = rem - y * W0_;
        list0[r] = (z << 16) | (y << 8) | x;
    } else idx0[c] = -1;
}

// ---------------- compact level 1/2 (stride-2 depth pooling of parent idx grid) ----------------
__global__ void k_compact_dn(const int* idxsrc, int* idxdst, int* listdst, int* cnt,
                             int ncell){
    int c = blockIdx.x * 256 + threadIdx.x;
    if (c >= ncell) return;
    int d = c / HW_; int rem = c - d * HW_;
    int y = rem / W0_; int x = rem - y * W0_;
    bool act = false;
    #pragma unroll
    for (int j = 0; j < 3; ++j)
        act = act || (idxsrc[((2*d + j)*H0_ + y)*W0_ + x] >= 0);
    if (act){
        int r = atomicAdd(cnt, 1);
        idxdst[c] = r;
        listdst[r] = (d << 16) | (y << 8) | x;
    } else idxdst[c] = -1;
}

// ---------------- scatter fp32 voxel features (atomic accumulate, matches ref scatter-add) ----------------
__global__ void k_scatter(const float* vf, const int* coors, const int* idx0, float* feat0f){
    int u = blockIdx.x * 256 + threadIdx.x;
    if (u >= NV_ * 16) return;
    int v = u >> 4, c8 = u & 15;
    int z = coors[v*4+1], y = coors[v*4+2], x = coors[v*4+3];
    int row = idx0[(z*H0_ + y)*W0_ + x];
    float* dst = feat0f + (long)row * 128 + c8 * 8;
    const float* sp = vf + (long)v * 128 + c8 * 8;
    #pragma unroll
    for (int i = 0; i < 8; ++i) atomicAdd(dst + i, sp[i]);
}

// ---------------- fp32 -> bf16 convert (exact except duplicate-summed cells) ----------------
__global__ void k_convert(const float* f, short* b, const int* cntp){
    int n = cntp[0] * 128;
    int i = blockIdx.x * 256 + threadIdx.x;
    if (i < n) b[i] = f2bf(f[i]);
}

// ---------------- 27-neighbor table ----------------
__global__ void k_nbr(const int* list, const int* idxg, int* nbrout, const int* cntp, int Dd){
    int site = blockIdx.x * 256 + threadIdx.x;
    int j = blockIdx.y;
    if (site >= *cntp) return;
    int cell = list[site];
    int z = cell >> 16, y = (cell >> 8) & 255, x = cell & 255;
    int nz = z + j/9 - 1, ny = y + (j/3)%3 - 1, nx = x + j%3 - 1;
    int r = -1;
    if (nz >= 0 && nz < Dd && ny >= 0 && ny < H0_ && nx >= 0 && nx < W0_)
        r = idxg[(nz*H0_ + ny)*W0_ + nx];
    nbrout[site*27 + j] = r;
}

// ---------------- 3-tap downsample neighbor table ----------------
__global__ void k_dnnbr(const int* list, const int* idxsrc, int* nbrout, const int* cntp){
    int site = blockIdx.x * 256 + threadIdx.x;
    int j = blockIdx.y;
    if (site >= *cntp) return;
    int cell = list[site];
    int d = cell >> 16, y = (cell >> 8) & 255, x = cell & 255;
    nbrout[site*3 + j] = idxsrc[((2*d + j)*H0_ + y)*W0_ + x];
}

// ---------------- gather-GEMM: C[M x 64] = gatherA[M x NNBR*128] @ B, BN+ReLU epilogue ----------------
// A rows: 128 bf16 per neighbor (layer1: 128 real channels; later layers: hi/lo split of 64).
// Non-final epilogue stores hi/lo bf16 pair; final epilogue scatters fp32 into d_out.
template<int NNBR, bool FINAL>
__global__ __launch_bounds__(256) void k_gemm(
    const int4* __restrict__ featA, const int* __restrict__ nbr,
    const short* __restrict__ Bs, short* __restrict__ out,
    const int* __restrict__ cntp,
    const float* __restrict__ scale, const float* __restrict__ shift,
    const int* __restrict__ list, float* __restrict__ dout)
{
    __shared__ short Alds[64 * 136];   // 64 rows x (128 + 8 pad) bf16
    int M = *cntp;
    int m0 = blockIdx.x * 64;
    if (m0 >= M) return;
    int tid = threadIdx.x;
    int wave = tid >> 6, lane = tid & 63;
    floatx4 acc[4] = {};

    for (int j = 0; j < NNBR; ++j){
        // stage neighbor j: 64 rows x 16 int4
        #pragma unroll
        for (int it = 0; it < 4; ++it){
            int u = tid + it * 256;
            int s = u >> 4, c = u & 15;
            int site = m0 + s;
            int r = (site < M) ? nbr[site * NNBR + j] : -1;
            int4 val = {0,0,0,0};
            if (r >= 0) val = featA[(long)r * 16 + c];
            *(int4*)&Alds[s * 136 + c * 8] = val;
        }
        __syncthreads();
        #pragma unroll
        for (int kc = 0; kc < 4; ++kc){
            bf16x8 a = *(const bf16x8*)&Alds[(wave*16 + (lane & 15)) * 136 + kc*32 + (lane >> 4)*8];
            const bf16x8* bp = (const bf16x8*)(Bs + (((j*4 + kc)*4)*64 + lane) * 8);
            #pragma unroll
            for (int nt = 0; nt < 4; ++nt){
                bf16x8 b = bp[nt * 64];
                acc[nt] = __builtin_amdgcn_mfma_f32_16x16x32_bf16(a, b, acc[nt], 0, 0, 0);
            }
        }
        __syncthreads();
    }

    // epilogue: C/D layout col = lane&15, row = (lane>>4)*4 + reg
    int n16 = lane & 15;
    int mb = wave * 16 + (lane >> 4) * 4;
    #pragma unroll
    for (int nt = 0; nt < 4; ++nt){
        int n = nt * 16 + n16;
        float sc = scale[n], sh = shift[n];
        #pragma unroll
        for (int r = 0; r < 4; ++r){
            int site = m0 + mb + r;
            if (site < M){
                float y = fmaxf(acc[nt][r] * sc + sh, 0.f);
                if (FINAL){
                    int cell = list[site];
                    int d = cell >> 16, yy = (cell >> 8) & 255, xx = cell & 255;
                    dout[((n*4 + d)*H0_ + yy)*W0_ + xx] = y;
                } else {
                    short hi = f2bf(y);
                    float lo = y - bf2f(hi);
                    out[(long)site*128 + n]      = hi;
                    out[(long)site*128 + 64 + n] = f2bf(lo);
                }
            }
        }
    }
}

extern "C" void kernel_launch(void* const* d_in, const int* in_sizes, int n_in,
                              void* d_out, int out_size, void* d_ws, size_t ws_size,
                              hipStream_t stream){
    const float* vf   = (const float*)d_in[0];
    const int*   coors= (const int*)  d_in[1];
    const float* w1   = (const float*)d_in[3];
    const float* wd1  = (const float*)d_in[4];
    const float* w2   = (const float*)d_in[5];
    const float* w3   = (const float*)d_in[6];
    const float* wd2  = (const float*)d_in[7];
    const float* bng  = (const float*)d_in[8];
    const float* bnb  = (const float*)d_in[9];
    const float* bnm  = (const float*)d_in[10];
    const float* bnv  = (const float*)d_in[11];
    float* dout = (float*)d_out;

    char* ws = (char*)d_ws;
    size_t off = 0;
    auto alloc = [&](size_t bytes)->char* {
        char* p = ws + off;
        off += (bytes + 255) & ~(size_t)255;
        return p;
    };

    int*   counters = (int*)  alloc(256);                    // [0]=cnt0 [1]=cnt1 [2]=cnt2
    int*   idx0     = (int*)  alloc((size_t)NCELL0 * 4);
    int*   idx1     = (int*)  alloc((size_t)NCELL1 * 4);
    int*   idx2     = (int*)  alloc((size_t)NCELL2 * 4);
    int*   list0    = (int*)  alloc((size_t)CAP0 * 4);
    int*   list1    = (int*)  alloc((size_t)CAP1 * 4);
    int*   list2    = (int*)  alloc((size_t)CAP2 * 4);
    float* feat0f   = (float*)alloc((size_t)CAP0 * 128 * 4); // fp32 scatter accum; feat2 aliases it later
    short* feat0b   = (short*)alloc((size_t)CAP0 * 128 * 2);
    short* feat1    = (short*)alloc((size_t)CAP0 * 128 * 2);
    short* featd1   = (short*)alloc((size_t)CAP1 * 128 * 2);
    short* feat3    = (short*)alloc((size_t)CAP1 * 128 * 2);
    int*   nbr0     = (int*)  alloc((size_t)CAP0 * 27 * 4);
    int*   nbr1     = (int*)  alloc((size_t)CAP1 * 27 * 4);
    int*   dnb1     = (int*)  alloc((size_t)CAP1 * 3 * 4);
    int*   dnb2     = (int*)  alloc((size_t)CAP2 * 3 * 4);
    short* B1  = (short*)alloc((size_t)3456 * 64 * 2);
    short* B2  = (short*)alloc((size_t)3456 * 64 * 2);
    short* B3  = (short*)alloc((size_t)3456 * 64 * 2);
    short* Bd1 = (short*)alloc((size_t)384 * 64 * 2);
    short* Bd2 = (short*)alloc((size_t)384 * 64 * 2);
    float* bnscale = (float*)alloc(5 * 64 * 4);
    float* bnshift = (float*)alloc(5 * 64 * 4);
    // feat2 (CAP1*128 shorts = 20.48MB) aliases feat0f (20.48MB), dead after k_convert
    short* feat2 = (short*)feat0f;

    // ---- zero what must be zero every call (ws/d_out are poisoned 0xAA) ----
    k_zero<<<1, 256, 0, stream>>>((int4*)counters, 16);
    k_zero<<<1024, 256, 0, stream>>>((int4*)idx0, (long)NCELL0 * 4 / 16);
    k_zero<<<2048, 256, 0, stream>>>((int4*)feat0f, (long)CAP0 * 128 * 4 / 16);
    k_zero<<<2048, 256, 0, stream>>>((int4*)dout, (long)out_size * 4 / 16);

    // ---- constants ----
    k_bnprep<<<2, 256, 0, stream>>>(bng, bnb, bnm, bnv, bnscale, bnshift);
    k_repack<<<(3456*64)/256, 256, 0, stream>>>(w1,  B1,  3456, 128, 27);
    k_repack<<<(3456*64)/256, 256, 0, stream>>>(w2,  B2,  3456,  64, 27);
    k_repack<<<(3456*64)/256, 256, 0, stream>>>(w3,  B3,  3456,  64, 27);
    k_repack<<<(384*64)/256, 256, 0, stream>>>(wd1, Bd1, 384,   64, 3);
    k_repack<<<(384*64)/256, 256, 0, stream>>>(wd2, Bd2, 384,   64, 3);

    // ---- build sparse structure ----
    k_mark<<<(NV_ + 255)/256, 256, 0, stream>>>(coors, idx0);
    k_compact0<<<(NCELL0 + 255)/256, 256, 0, stream>>>(idx0, list0, counters + 0);
    k_scatter<<<(NV_*16)/256, 256, 0, stream>>>(vf, coors, idx0, feat0f);
    k_convert<<<(CAP0*128)/256, 256, 0, stream>>>(feat0f, feat0b, counters + 0);
    k_compact_dn<<<(NCELL1 + 255)/256, 256, 0, stream>>>(idx0, idx1, list1, counters + 1, NCELL1);
    k_compact_dn<<<(NCELL2 + 255)/256, 256, 0, stream>>>(idx1, idx2, list2, counters + 2, NCELL2);

    dim3 g0((CAP0 + 255)/256, 27), g1((CAP1 + 255)/256, 27);
    k_nbr<<<g0, 256, 0, stream>>>(list0, idx0, nbr0, counters + 0, D0_);
    k_nbr<<<g1, 256, 0, stream>>>(list1, idx1, nbr1, counters + 1, D1_);
    dim3 gd1((CAP1 + 255)/256, 3), gd2((CAP2 + 255)/256, 3);
    k_dnnbr<<<gd1, 256, 0, stream>>>(list1, idx0, dnb1, counters + 1);
    k_dnnbr<<<gd2, 256, 0, stream>>>(list2, idx1, dnb2, counters + 2);

    // ---- the five gather-GEMMs ----
    k_gemm<27,false><<<CAP0/64, 256, 0, stream>>>((const int4*)feat0b, nbr0, B1, feat1,
        counters + 0, bnscale + 0,   bnshift + 0,   nullptr, nullptr);
    k_gemm<3,false><<<CAP1/64, 256, 0, stream>>>((const int4*)feat1, dnb1, Bd1, featd1,
        counters + 1, bnscale + 64,  bnshift + 64,  nullptr, nullptr);
    k_gemm<27,false><<<CAP1/64, 256, 0, stream>>>((const int4*)featd1, nbr1, B2, feat2,
        counters + 1, bnscale + 128, bnshift + 128, nullptr, nullptr);
    k_gemm<27,false><<<CAP1/64, 256, 0, stream>>>((const int4*)feat2, nbr1, B3, feat3,
        counters + 1, bnscale + 192, bnshift + 192, nullptr, nullptr);
    k_gemm<3,true><<<CAP2/64, 256, 0, stream>>>((const int4*)feat3, dnb2, Bd2, nullptr,
        counters + 2, bnscale + 256, bnshift + 256, list2, dout);
}

// Round 4
// 598.927 us; speedup vs baseline: 1.3745x; 1.3745x over previous
//
#include <hip/hip_runtime.h>

typedef float floatx4 __attribute__((ext_vector_type(4)));
typedef __bf16 bf16x8 __attribute__((ext_vector_type(8)));

#define D0_ 19
#define H0_ 200
#define W0_ 176
#define HW_ (H0_*W0_)          // 35200
#define NCELL0 (D0_*HW_)       // 668800
#define D1_ 9
#define NCELL1 (D1_*HW_)       // 316800
#define D2_ 4
#define NCELL2 (D2_*HW_)       // 140800
#define NV_ 40000
#define CAP0 40000
#define CAP1 80000
#define CAP2 140800
#define EPS_ 1e-3f

__device__ __forceinline__ float bf2f(short s){
    union { unsigned u; float f; } x; x.u = ((unsigned)(unsigned short)s) << 16; return x.f;
}
__device__ __forceinline__ short f2bf(float f){
    union { float f; unsigned u; } x; x.f = f;
    unsigned r = x.u + 0x7fffu + ((x.u >> 16) & 1u);
    return (short)(r >> 16);
}

// ---------------- fused constant prep: BN consts + 5 weight repacks ----------------
// repack dest: Bout[ ((kchunk*4 + ntile)*64 + lane)*8 + jj ], lane = ((k>>3)&3)*16 + (n&15)
__device__ __forceinline__ void repack_one(const float* w, short* Bout, int i, int KCsrc, int NSP){
    int k = i >> 6, n = i & 63;
    int ci = k & 127;
    int cis = (KCsrc == 128) ? ci : (ci & 63);
    short val = f2bf(w[(n * KCsrc + cis) * NSP + (k >> 7)]);
    int kc = k >> 5, lanehi = (k >> 3) & 3, jj = k & 7;
    int nt = n >> 4, lane = lanehi * 16 + (n & 15);
    Bout[((kc * 4 + nt) * 64 + lane) * 8 + jj] = val;
}

#define RP_BIG (3456*64)   // 221184
#define RP_SML (384*64)    // 24576

__global__ void k_prep(const float* w1, const float* w2, const float* w3,
                       const float* wd1, const float* wd2,
                       short* B1, short* B2, short* B3, short* Bd1, short* Bd2,
                       const float* g, const float* b, const float* m, const float* v,
                       float* scale, float* shift){
    int i = blockIdx.x * 256 + threadIdx.x;
    if (i < RP_BIG){ repack_one(w1, B1, i, 128, 27); return; }
    i -= RP_BIG;
    if (i < RP_BIG){ repack_one(w2, B2, i, 64, 27); return; }
    i -= RP_BIG;
    if (i < RP_BIG){ repack_one(w3, B3, i, 64, 27); return; }
    i -= RP_BIG;
    if (i < RP_SML){ repack_one(wd1, Bd1, i, 64, 3); return; }
    i -= RP_SML;
    if (i < RP_SML){ repack_one(wd2, Bd2, i, 64, 3); return; }
    i -= RP_SML;
    if (i < 5*64){
        float s = g[i] / sqrtf(v[i] + EPS_);
        scale[i] = s;
        shift[i] = b[i] - m[i] * s;
    }
}
#define PREP_TOT (3*RP_BIG + 2*RP_SML + 5*64)

// ---------------- voxel count per cell ----------------
__global__ void k_count(const int* coors, int* cntg){
    int v = blockIdx.x * 256 + threadIdx.x;
    if (v >= NV_) return;
    int z = coors[v*4+1], y = coors[v*4+2], x = coors[v*4+3];
    atomicAdd(&cntg[(z*H0_ + y)*W0_ + x], 1);
}

// ---------------- compact level 0 ----------------
__global__ void k_compact0(const int* cntg, int* idx0, int* list0, int* cnt0){
    int c = blockIdx.x * 256 + threadIdx.x;
    if (c >= NCELL0) return;
    if (cntg[c] > 0){
        int r = atomicAdd(cnt0, 1);
        idx0[c] = r;
        int z = c / HW_; int rem = c - z * HW_;
        int y = rem / W0_; int x = rem - y * W0_;
        list0[r] = (z << 16) | (y << 8) | x;
    } else idx0[c] = -1;
}

// ---------------- compact level 1/2 (stride-2 depth pooling of parent idx grid) ----------------
__global__ void k_compact_dn(const int* idxsrc, int* idxdst, int* listdst, int* cnt,
                             int ncell){
    int c = blockIdx.x * 256 + threadIdx.x;
    if (c >= ncell) return;
    int d = c / HW_; int rem = c - d * HW_;
    int y = rem / W0_; int x = rem - y * W0_;
    bool act = false;
    #pragma unroll
    for (int j = 0; j < 3; ++j)
        act = act || (idxsrc[((2*d + j)*H0_ + y)*W0_ + x] >= 0);
    if (act){
        int r = atomicAdd(cnt, 1);
        idxdst[c] = r;
        listdst[r] = (d << 16) | (y << 8) | x;
    } else idxdst[c] = -1;
}

// ---------------- scatter fp32 features: 32 threads/voxel, fast path for unique cells ----------------
__global__ void k_scatter(const float* vf, const int* coors, const int* cntg,
                          const int* idx0, float* feat0f){
    int u = blockIdx.x * 256 + threadIdx.x;
    if (u >= NV_ * 32) return;
    int v = u >> 5, c4 = u & 31;             // 32 threads x float4 = 128 channels
    int z = coors[v*4+1], y = coors[v*4+2], x = coors[v*4+3];
    int cell = (z*H0_ + y)*W0_ + x;
    int row = idx0[cell];
    float4 s = ((const float4*)(vf + (long)v * 128))[c4];
    float* dst = feat0f + (long)row * 128 + c4 * 4;
    if (cntg[cell] == 1){
        *(float4*)dst = s;
    } else {
        atomicAdd(dst+0, s.x); atomicAdd(dst+1, s.y);
        atomicAdd(dst+2, s.z); atomicAdd(dst+3, s.w);
    }
}

// ---------------- fp32 -> bf16 convert (8 per thread) ----------------
__global__ void k_convert(const float* f, short* b, const int* cntp){
    int n8 = cntp[0] * 16;
    int i = blockIdx.x * 256 + threadIdx.x;
    if (i >= n8) return;
    float4 a = ((const float4*)f)[i*2], c = ((const float4*)f)[i*2+1];
    short o[8] = { f2bf(a.x), f2bf(a.y), f2bf(a.z), f2bf(a.w),
                   f2bf(c.x), f2bf(c.y), f2bf(c.z), f2bf(c.w) };
    ((int4*)b)[i] = *(int4*)o;
}

// ---------------- fused neighbor tables (coalesced u = site*NT + j) ----------------
__global__ void k_nbrs(const int* list0, const int* list1, const int* list2,
                       const int* idx0, const int* idx1,
                       int* nbr0, int* nbr1, int* dnb1, int* dnb2,
                       const int* counters){
    int job = blockIdx.y;
    int u = blockIdx.x * 256 + threadIdx.x;
    if (job <= 1){
        int M = counters[job];
        if (u >= M * 27) return;
        int site = u / 27, j = u - site * 27;
        const int* list = job ? list1 : list0;
        const int* idxg = job ? idx1 : idx0;
        int Dd = job ? D1_ : D0_;
        int cell = list[site];
        int z = cell >> 16, y = (cell >> 8) & 255, x = cell & 255;
        int nz = z + j/9 - 1, ny = y + (j/3)%3 - 1, nx = x + j%3 - 1;
        int r = -1;
        if ((unsigned)nz < (unsigned)Dd && (unsigned)ny < H0_ && (unsigned)nx < W0_)
            r = idxg[(nz*H0_ + ny)*W0_ + nx];
        (job ? nbr1 : nbr0)[u] = r;
    } else {
        int M = counters[job - 1];
        if (u >= M * 3) return;
        int site = u / 3, j = u - site * 3;
        const int* list = (job == 2) ? list1 : list2;
        const int* idxg = (job == 2) ? idx0 : idx1;
        int cell = list[site];
        int d = cell >> 16, y = (cell >> 8) & 255, x = cell & 255;
        (job == 2 ? dnb1 : dnb2)[u] = idxg[((2*d + j)*H0_ + y)*W0_ + x];
    }
}

// ---------------- gather-GEMM: C[M x 64] = gatherA[M x NNBR*128] @ B, BN+ReLU ----------------
// Double-buffered LDS (1 barrier/tap), nbr indices preloaded to LDS,
// 64B-contiguous staging per thread.
template<int NNBR, bool FINAL>
__global__ __launch_bounds__(256) void k_gemm(
    const int4* __restrict__ featA, const int* __restrict__ nbr,
    const short* __restrict__ Bs, short* __restrict__ out,
    const int* __restrict__ cntp,
    const float* __restrict__ scale, const float* __restrict__ shift,
    const int* __restrict__ list, float* __restrict__ dout)
{
    __shared__ short Alds[2][64 * 136];      // 2 x (64 rows x (128+8 pad))
    __shared__ int nbrLds[64 * NNBR];
    int M = *cntp;
    int m0 = blockIdx.x * 64;
    if (m0 >= M) return;
    int tid = threadIdx.x;
    int wave = tid >> 6, lane = tid & 63;
    floatx4 acc[4] = {};

    // preload this block's neighbor indices (contiguous in nbr)
    for (int u = tid; u < 64 * NNBR; u += 256){
        int site = m0 + u / NNBR;
        nbrLds[u] = (site < M) ? nbr[(long)m0 * NNBR + u] : -1;
    }
    __syncthreads();

    int srow = tid >> 2, c4 = tid & 3;       // each thread: 64B chunk of one row
    short* dstb[2] = { &Alds[0][srow*136 + c4*32], &Alds[1][srow*136 + c4*32] };

    auto stage = [&](int j, int buf){
        int r = nbrLds[srow * NNBR + j];
        int4 v0 = {0,0,0,0}, v1 = v0, v2 = v0, v3 = v0;
        if (r >= 0){
            const int4* src = featA + ((long)r * 16 + c4 * 4);
            v0 = src[0]; v1 = src[1]; v2 = src[2]; v3 = src[3];
        }
        short* d = dstb[buf];
        *(int4*)(d+0) = v0; *(int4*)(d+8) = v1; *(int4*)(d+16) = v2; *(int4*)(d+24) = v3;
    };

    stage(0, 0);
    __syncthreads();
    int aoff = (wave*16 + (lane & 15)) * 136 + (lane >> 4) * 8;
    for (int j = 0; j < NNBR; ++j){
        const short* Ab = Alds[j & 1];
        bf16x8 a[4];
        #pragma unroll
        for (int kc = 0; kc < 4; ++kc)
            a[kc] = *(const bf16x8*)&Ab[aoff + kc*32];
        if (j + 1 < NNBR) stage(j + 1, (j + 1) & 1);
        #pragma unroll
        for (int kc = 0; kc < 4; ++kc){
            const bf16x8* bp = (const bf16x8*)(Bs + (((j*4 + kc)*4)*64 + lane) * 8);
            #pragma unroll
            for (int nt = 0; nt < 4; ++nt)
                acc[nt] = __builtin_amdgcn_mfma_f32_16x16x32_bf16(a[kc], bp[nt*64], acc[nt], 0, 0, 0);
        }
        __syncthreads();
    }

    // epilogue: C/D layout col = lane&15, row = (lane>>4)*4 + reg
    int n16 = lane & 15;
    int mb = wave * 16 + (lane >> 4) * 4;
    #pragma unroll
    for (int nt = 0; nt < 4; ++nt){
        int n = nt * 16 + n16;
        float sc = scale[n], sh = shift[n];
        #pragma unroll
        for (int r = 0; r < 4; ++r){
            int site = m0 + mb + r;
            if (site < M){
                float y = fmaxf(acc[nt][r] * sc + sh, 0.f);
                if (FINAL){
                    int cell = list[site];
                    int d = cell >> 16, yy = (cell >> 8) & 255, xx = cell & 255;
                    dout[((n*4 + d)*H0_ + yy)*W0_ + xx] = y;
                } else {
                    short hi = f2bf(y);
                    float lo = y - bf2f(hi);
                    out[(long)site*128 + n]      = hi;
                    out[(long)site*128 + 64 + n] = f2bf(lo);
                }
            }
        }
    }
}

extern "C" void kernel_launch(void* const* d_in, const int* in_sizes, int n_in,
                              void* d_out, int out_size, void* d_ws, size_t ws_size,
                              hipStream_t stream){
    const float* vf   = (const float*)d_in[0];
    const int*   coors= (const int*)  d_in[1];
    const float* w1   = (const float*)d_in[3];
    const float* wd1  = (const float*)d_in[4];
    const float* w2   = (const float*)d_in[5];
    const float* w3   = (const float*)d_in[6];
    const float* wd2  = (const float*)d_in[7];
    const float* bng  = (const float*)d_in[8];
    const float* bnb  = (const float*)d_in[9];
    const float* bnm  = (const float*)d_in[10];
    const float* bnv  = (const float*)d_in[11];
    float* dout = (float*)d_out;

    char* ws = (char*)d_ws;
    size_t off = 0;
    auto alloc = [&](size_t bytes)->char* {
        char* p = ws + off;
        off += (bytes + 255) & ~(size_t)255;
        return p;
    };

    int*   counters = (int*)  alloc(256);                    // [0]=cnt0 [1]=cnt1 [2]=cnt2
    int*   cntg     = (int*)  alloc((size_t)NCELL0 * 4);     // contiguous after counters
    int*   idx0     = (int*)  alloc((size_t)NCELL0 * 4);
    int*   idx1     = (int*)  alloc((size_t)NCELL1 * 4);
    int*   idx2     = (int*)  alloc((size_t)NCELL2 * 4);
    int*   list0    = (int*)  alloc((size_t)CAP0 * 4);
    int*   list1    = (int*)  alloc((size_t)CAP1 * 4);
    int*   list2    = (int*)  alloc((size_t)CAP2 * 4);
    float* feat0f   = (float*)alloc((size_t)CAP0 * 128 * 4); // fp32 scatter accum; feat2 aliases later
    short* feat0b   = (short*)alloc((size_t)CAP0 * 128 * 2);
    short* feat1    = (short*)alloc((size_t)CAP0 * 128 * 2);
    short* featd1   = (short*)alloc((size_t)CAP1 * 128 * 2);
    short* feat3    = (short*)alloc((size_t)CAP1 * 128 * 2);
    int*   nbr0     = (int*)  alloc((size_t)CAP0 * 27 * 4);
    int*   nbr1     = (int*)  alloc((size_t)CAP1 * 27 * 4);
    int*   dnb1     = (int*)  alloc((size_t)CAP1 * 3 * 4);
    int*   dnb2     = (int*)  alloc((size_t)CAP2 * 3 * 4);
    short* B1  = (short*)alloc((size_t)3456 * 64 * 2);
    short* B2  = (short*)alloc((size_t)3456 * 64 * 2);
    short* B3  = (short*)alloc((size_t)3456 * 64 * 2);
    short* Bd1 = (short*)alloc((size_t)384 * 64 * 2);
    short* Bd2 = (short*)alloc((size_t)384 * 64 * 2);
    float* bnscale = (float*)alloc(5 * 64 * 4);
    float* bnshift = (float*)alloc(5 * 64 * 4);
    short* feat2 = (short*)feat0f;   // alias: feat0f dead after k_convert

    // ---- zero (ws/d_out poisoned 0xAA) ----
    hipMemsetAsync(counters, 0, 256 + (size_t)NCELL0 * 4, stream);   // counters + cntg
    hipMemsetAsync(feat0f, 0, (size_t)CAP0 * 128 * 4, stream);
    hipMemsetAsync(dout, 0, (size_t)out_size * 4, stream);

    // ---- constants (one fused launch) ----
    k_prep<<<(PREP_TOT + 255)/256, 256, 0, stream>>>(w1, w2, w3, wd1, wd2,
        B1, B2, B3, Bd1, Bd2, bng, bnb, bnm, bnv, bnscale, bnshift);

    // ---- sparse structure ----
    k_count<<<(NV_ + 255)/256, 256, 0, stream>>>(coors, cntg);
    k_compact0<<<(NCELL0 + 255)/256, 256, 0, stream>>>(cntg, idx0, list0, counters + 0);
    k_scatter<<<(NV_*32 + 255)/256, 256, 0, stream>>>(vf, coors, cntg, idx0, feat0f);
    k_convert<<<(CAP0*16 + 255)/256, 256, 0, stream>>>(feat0f, feat0b, counters + 0);
    k_compact_dn<<<(NCELL1 + 255)/256, 256, 0, stream>>>(idx0, idx1, list1, counters + 1, NCELL1);
    k_compact_dn<<<(NCELL2 + 255)/256, 256, 0, stream>>>(idx1, idx2, list2, counters + 2, NCELL2);

    dim3 gn((CAP1*27 + 255)/256, 4);
    k_nbrs<<<gn, 256, 0, stream>>>(list0, list1, list2, idx0, idx1,
                                   nbr0, nbr1, dnb1, dnb2, counters);

    // ---- the five gather-GEMMs ----
    k_gemm<27,false><<<CAP0/64, 256, 0, stream>>>((const int4*)feat0b, nbr0, B1, feat1,
        counters + 0, bnscale + 0,   bnshift + 0,   nullptr, nullptr);
    k_gemm<3,false><<<CAP1/64, 256, 0, stream>>>((const int4*)feat1, dnb1, Bd1, featd1,
        counters + 1, bnscale + 64,  bnshift + 64,  nullptr, nullptr);
    k_gemm<27,false><<<CAP1/64, 256, 0, stream>>>((const int4*)featd1, nbr1, B2, feat2,
        counters + 1, bnscale + 128, bnshift + 128, nullptr, nullptr);
    k_gemm<27,false><<<CAP1/64, 256, 0, stream>>>((const int4*)feat2, nbr1, B3, feat3,
        counters + 1, bnscale + 192, bnshift + 192, nullptr, nullptr);
    k_gemm<3,true><<<CAP2/64, 256, 0, stream>>>((const int4*)feat3, dnb2, Bd2, nullptr,
        counters + 2, bnscale + 256, bnshift + 256, list2, dout);
}

// Round 5
// 450.191 us; speedup vs baseline: 1.8287x; 1.3304x over previous
//
#include <hip/hip_runtime.h>

typedef float floatx4 __attribute__((ext_vector_type(4)));
typedef __bf16 bf16x8 __attribute__((ext_vector_type(8)));

#define D0_ 19
#define H0_ 200
#define W0_ 176
#define HW_ (H0_*W0_)          // 35200
#define NCELL0 (D0_*HW_)       // 668800
#define D1_ 9
#define NCELL1 (D1_*HW_)       // 316800
#define D2_ 4
#define NCELL2 (D2_*HW_)       // 140800
#define NV_ 40000
#define CAP0 40000
#define CAP1 80000
#define CAP2 140800
#define EPS_ 1e-3f

__device__ __forceinline__ float bf2f(short s){
    union { unsigned u; float f; } x; x.u = ((unsigned)(unsigned short)s) << 16; return x.f;
}
__device__ __forceinline__ short f2bf(float f){
    union { float f; unsigned u; } x; x.f = f;
    unsigned r = x.u + 0x7fffu + ((x.u >> 16) & 1u);
    return (short)(r >> 16);
}

// ---------------- fused constant prep: BN consts + 5 weight repacks ----------------
// repack dest: Bout[ ((kchunk*4 + ntile)*64 + lane)*8 + jj ], lane = ((k>>3)&3)*16 + (n&15)
__device__ __forceinline__ void repack_one(const float* w, short* Bout, int i, int KCsrc, int NSP){
    int k = i >> 6, n = i & 63;
    int ci = k & 127;
    int cis = (KCsrc == 128) ? ci : (ci & 63);
    short val = f2bf(w[(n * KCsrc + cis) * NSP + (k >> 7)]);
    int kc = k >> 5, lanehi = (k >> 3) & 3, jj = k & 7;
    int nt = n >> 4, lane = lanehi * 16 + (n & 15);
    Bout[((kc * 4 + nt) * 64 + lane) * 8 + jj] = val;
}

#define RP_BIG (3456*64)   // 221184
#define RP_SML (384*64)    // 24576

__global__ void k_prep(const float* w1, const float* w2, const float* w3,
                       const float* wd1, const float* wd2,
                       short* B1, short* B2, short* B3, short* Bd1, short* Bd2,
                       const float* g, const float* b, const float* m, const float* v,
                       float* scale, float* shift){
    int i = blockIdx.x * 256 + threadIdx.x;
    if (i < RP_BIG){ repack_one(w1, B1, i, 128, 27); return; }
    i -= RP_BIG;
    if (i < RP_BIG){ repack_one(w2, B2, i, 64, 27); return; }
    i -= RP_BIG;
    if (i < RP_BIG){ repack_one(w3, B3, i, 64, 27); return; }
    i -= RP_BIG;
    if (i < RP_SML){ repack_one(wd1, Bd1, i, 64, 3); return; }
    i -= RP_SML;
    if (i < RP_SML){ repack_one(wd2, Bd2, i, 64, 3); return; }
    i -= RP_SML;
    if (i < 5*64){
        float s = g[i] / sqrtf(v[i] + EPS_);
        scale[i] = s;
        shift[i] = b[i] - m[i] * s;
    }
}
#define PREP_TOT (3*RP_BIG + 2*RP_SML + 5*64)

// ---------------- voxel count per cell (distinct addresses - fine) ----------------
__global__ void k_count(const int* coors, int* cntg){
    int v = blockIdx.x * 256 + threadIdx.x;
    if (v >= NV_) return;
    int z = coors[v*4+1], y = coors[v*4+2], x = coors[v*4+3];
    atomicAdd(&cntg[(z*H0_ + y)*W0_ + x], 1);
}

// ---------------- block-aggregated row assignment: ONE atomic per block ----------------
__device__ __forceinline__ int blk_rank(bool act, int* cnt, int& r_out){
    unsigned long long mask = __ballot(act);
    int lane = threadIdx.x & 63, wid = threadIdx.x >> 6;
    int wrank = __popcll(mask & ((1ull << lane) - 1));
    __shared__ int ws[4];
    __shared__ int blkbase;
    if (lane == 0) ws[wid] = __popcll(mask);
    __syncthreads();
    if (threadIdx.x == 0){
        int t0 = ws[0], t1 = ws[1], t2 = ws[2], t3 = ws[3];
        int tot = t0 + t1 + t2 + t3;
        blkbase = tot ? atomicAdd(cnt, tot) : 0;
        ws[0] = 0; ws[1] = t0; ws[2] = t0 + t1; ws[3] = t0 + t1 + t2;
    }
    __syncthreads();
    r_out = blkbase + ws[wid] + wrank;
    return 0;
}

// ---------------- compact level 0 ----------------
__global__ void k_compact0(const int* cntg, int* idx0, int* list0, int* cnt0){
    int c = blockIdx.x * 256 + threadIdx.x;
    bool act = (c < NCELL0) && (cntg[c] > 0);
    int r; blk_rank(act, cnt0, r);
    if (c >= NCELL0) return;
    if (act){
        idx0[c] = r;
        int z = c / HW_; int rem = c - z * HW_;
        int y = rem / W0_; int x = rem - y * W0_;
        list0[r] = (z << 16) | (y << 8) | x;
    } else idx0[c] = -1;
}

// ---------------- compact level 1/2 (stride-2 depth pooling of parent idx grid) ----------------
__global__ void k_compact_dn(const int* idxsrc, int* idxdst, int* listdst, int* cnt,
                             int ncell){
    int c = blockIdx.x * 256 + threadIdx.x;
    bool act = false;
    int d = 0, y = 0, x = 0;
    if (c < ncell){
        d = c / HW_; int rem = c - d * HW_;
        y = rem / W0_; x = rem - y * W0_;
        #pragma unroll
        for (int j = 0; j < 3; ++j)
            act = act || (idxsrc[((2*d + j)*H0_ + y)*W0_ + x] >= 0);
    }
    int r; blk_rank(act, cnt, r);
    if (c >= ncell) return;
    if (act){
        idxdst[c] = r;
        listdst[r] = (d << 16) | (y << 8) | x;
    } else idxdst[c] = -1;
}

// ---------------- scatter fp32 features: 32 threads/voxel, fast path for unique cells ----------------
__global__ void k_scatter(const float* vf, const int* coors, const int* cntg,
                          const int* idx0, float* feat0f){
    int u = blockIdx.x * 256 + threadIdx.x;
    if (u >= NV_ * 32) return;
    int v = u >> 5, c4 = u & 31;             // 32 threads x float4 = 128 channels
    int z = coors[v*4+1], y = coors[v*4+2], x = coors[v*4+3];
    int cell = (z*H0_ + y)*W0_ + x;
    int row = idx0[cell];
    float4 s = ((const float4*)(vf + (long)v * 128))[c4];
    float* dst = feat0f + (long)row * 128 + c4 * 4;
    if (cntg[cell] == 1){
        *(float4*)dst = s;
    } else {
        atomicAdd(dst+0, s.x); atomicAdd(dst+1, s.y);
        atomicAdd(dst+2, s.z); atomicAdd(dst+3, s.w);
    }
}

// ---------------- fp32 -> bf16 convert (8 per thread) ----------------
__global__ void k_convert(const float* f, short* b, const int* cntp){
    int n8 = cntp[0] * 16;
    int i = blockIdx.x * 256 + threadIdx.x;
    if (i >= n8) return;
    float4 a = ((const float4*)f)[i*2], c = ((const float4*)f)[i*2+1];
    short o[8] = { f2bf(a.x), f2bf(a.y), f2bf(a.z), f2bf(a.w),
                   f2bf(c.x), f2bf(c.y), f2bf(c.z), f2bf(c.w) };
    ((int4*)b)[i] = *(int4*)o;
}

// ---------------- fused neighbor tables (coalesced u = site*NT + j) ----------------
__global__ void k_nbrs(const int* list0, const int* list1, const int* list2,
                       const int* idx0, const int* idx1,
                       int* nbr0, int* nbr1, int* dnb1, int* dnb2,
                       const int* counters){
    int job = blockIdx.y;
    int u = blockIdx.x * 256 + threadIdx.x;
    if (job <= 1){
        int M = counters[job];
        if (u >= M * 27) return;
        int site = u / 27, j = u - site * 27;
        const int* list = job ? list1 : list0;
        const int* idxg = job ? idx1 : idx0;
        int Dd = job ? D1_ : D0_;
        int cell = list[site];
        int z = cell >> 16, y = (cell >> 8) & 255, x = cell & 255;
        int nz = z + j/9 - 1, ny = y + (j/3)%3 - 1, nx = x + j%3 - 1;
        int r = -1;
        if ((unsigned)nz < (unsigned)Dd && (unsigned)ny < H0_ && (unsigned)nx < W0_)
            r = idxg[(nz*H0_ + ny)*W0_ + nx];
        (job ? nbr1 : nbr0)[u] = r;
    } else {
        int M = counters[job - 1];
        if (u >= M * 3) return;
        int site = u / 3, j = u - site * 3;
        const int* list = (job == 2) ? list1 : list2;
        const int* idxg = (job == 2) ? idx0 : idx1;
        int cell = list[site];
        int d = cell >> 16, y = (cell >> 8) & 255, x = cell & 255;
        (job == 2 ? dnb1 : dnb2)[u] = idxg[((2*d + j)*H0_ + y)*W0_ + x];
    }
}

// ---------------- gather-GEMM: C[M x 64] = gatherA[M x NNBR*128] @ B, BN+ReLU ----------------
// Double-buffered LDS (1 barrier/tap), nbr indices preloaded to LDS,
// 64B-contiguous staging per thread.
template<int NNBR, bool FINAL>
__global__ __launch_bounds__(256) void k_gemm(
    const int4* __restrict__ featA, const int* __restrict__ nbr,
    const short* __restrict__ Bs, short* __restrict__ out,
    const int* __restrict__ cntp,
    const float* __restrict__ scale, const float* __restrict__ shift,
    const int* __restrict__ list, float* __restrict__ dout)
{
    __shared__ short Alds[2][64 * 136];      // 2 x (64 rows x (128+8 pad))
    __shared__ int nbrLds[64 * NNBR];
    int M = *cntp;
    int m0 = blockIdx.x * 64;
    if (m0 >= M) return;
    int tid = threadIdx.x;
    int wave = tid >> 6, lane = tid & 63;
    floatx4 acc[4] = {};

    // preload this block's neighbor indices (contiguous in nbr)
    for (int u = tid; u < 64 * NNBR; u += 256){
        int site = m0 + u / NNBR;
        nbrLds[u] = (site < M) ? nbr[(long)m0 * NNBR + u] : -1;
    }
    __syncthreads();

    int srow = tid >> 2, c4 = tid & 3;       // each thread: 64B chunk of one row
    short* dstb[2] = { &Alds[0][srow*136 + c4*32], &Alds[1][srow*136 + c4*32] };

    auto stage = [&](int j, int buf){
        int r = nbrLds[srow * NNBR + j];
        int4 v0 = {0,0,0,0}, v1 = v0, v2 = v0, v3 = v0;
        if (r >= 0){
            const int4* src = featA + ((long)r * 16 + c4 * 4);
            v0 = src[0]; v1 = src[1]; v2 = src[2]; v3 = src[3];
        }
        short* d = dstb[buf];
        *(int4*)(d+0) = v0; *(int4*)(d+8) = v1; *(int4*)(d+16) = v2; *(int4*)(d+24) = v3;
    };

    stage(0, 0);
    __syncthreads();
    int aoff = (wave*16 + (lane & 15)) * 136 + (lane >> 4) * 8;
    for (int j = 0; j < NNBR; ++j){
        const short* Ab = Alds[j & 1];
        bf16x8 a[4];
        #pragma unroll
        for (int kc = 0; kc < 4; ++kc)
            a[kc] = *(const bf16x8*)&Ab[aoff + kc*32];
        if (j + 1 < NNBR) stage(j + 1, (j + 1) & 1);
        #pragma unroll
        for (int kc = 0; kc < 4; ++kc){
            const bf16x8* bp = (const bf16x8*)(Bs + (((j*4 + kc)*4)*64 + lane) * 8);
            #pragma unroll
            for (int nt = 0; nt < 4; ++nt)
                acc[nt] = __builtin_amdgcn_mfma_f32_16x16x32_bf16(a[kc], bp[nt*64], acc[nt], 0, 0, 0);
        }
        __syncthreads();
    }

    // epilogue: C/D layout col = lane&15, row = (lane>>4)*4 + reg
    int n16 = lane & 15;
    int mb = wave * 16 + (lane >> 4) * 4;
    #pragma unroll
    for (int nt = 0; nt < 4; ++nt){
        int n = nt * 16 + n16;
        float sc = scale[n], sh = shift[n];
        #pragma unroll
        for (int r = 0; r < 4; ++r){
            int site = m0 + mb + r;
            if (site < M){
                float y = fmaxf(acc[nt][r] * sc + sh, 0.f);
                if (FINAL){
                    int cell = list[site];
                    int d = cell >> 16, yy = (cell >> 8) & 255, xx = cell & 255;
                    dout[((n*4 + d)*H0_ + yy)*W0_ + xx] = y;
                } else {
                    short hi = f2bf(y);
                    float lo = y - bf2f(hi);
                    out[(long)site*128 + n]      = hi;
                    out[(long)site*128 + 64 + n] = f2bf(lo);
                }
            }
        }
    }
}

extern "C" void kernel_launch(void* const* d_in, const int* in_sizes, int n_in,
                              void* d_out, int out_size, void* d_ws, size_t ws_size,
                              hipStream_t stream){
    const float* vf   = (const float*)d_in[0];
    const int*   coors= (const int*)  d_in[1];
    const float* w1   = (const float*)d_in[3];
    const float* wd1  = (const float*)d_in[4];
    const float* w2   = (const float*)d_in[5];
    const float* w3   = (const float*)d_in[6];
    const float* wd2  = (const float*)d_in[7];
    const float* bng  = (const float*)d_in[8];
    const float* bnb  = (const float*)d_in[9];
    const float* bnm  = (const float*)d_in[10];
    const float* bnv  = (const float*)d_in[11];
    float* dout = (float*)d_out;

    char* ws = (char*)d_ws;
    size_t off = 0;
    auto alloc = [&](size_t bytes)->char* {
        char* p = ws + off;
        off += (bytes + 255) & ~(size_t)255;
        return p;
    };

    int*   counters = (int*)  alloc(256);                    // [0]=cnt0 [1]=cnt1 [2]=cnt2
    int*   cntg     = (int*)  alloc((size_t)NCELL0 * 4);     // contiguous after counters
    int*   idx0     = (int*)  alloc((size_t)NCELL0 * 4);
    int*   idx1     = (int*)  alloc((size_t)NCELL1 * 4);
    int*   idx2     = (int*)  alloc((size_t)NCELL2 * 4);
    int*   list0    = (int*)  alloc((size_t)CAP0 * 4);
    int*   list1    = (int*)  alloc((size_t)CAP1 * 4);
    int*   list2    = (int*)  alloc((size_t)CAP2 * 4);
    float* feat0f   = (float*)alloc((size_t)CAP0 * 128 * 4); // fp32 scatter accum; feat2 aliases later
    short* feat0b   = (short*)alloc((size_t)CAP0 * 128 * 2);
    short* feat1    = (short*)alloc((size_t)CAP0 * 128 * 2);
    short* featd1   = (short*)alloc((size_t)CAP1 * 128 * 2);
    short* feat3    = (short*)alloc((size_t)CAP1 * 128 * 2);
    int*   nbr0     = (int*)  alloc((size_t)CAP0 * 27 * 4);
    int*   nbr1     = (int*)  alloc((size_t)CAP1 * 27 * 4);
    int*   dnb1     = (int*)  alloc((size_t)CAP1 * 3 * 4);
    int*   dnb2     = (int*)  alloc((size_t)CAP2 * 3 * 4);
    short* B1  = (short*)alloc((size_t)3456 * 64 * 2);
    short* B2  = (short*)alloc((size_t)3456 * 64 * 2);
    short* B3  = (short*)alloc((size_t)3456 * 64 * 2);
    short* Bd1 = (short*)alloc((size_t)384 * 64 * 2);
    short* Bd2 = (short*)alloc((size_t)384 * 64 * 2);
    float* bnscale = (float*)alloc(5 * 64 * 4);
    float* bnshift = (float*)alloc(5 * 64 * 4);
    short* feat2 = (short*)feat0f;   // alias: feat0f dead after k_convert

    // ---- zero (ws/d_out poisoned 0xAA) ----
    hipMemsetAsync(counters, 0, 256 + (size_t)NCELL0 * 4, stream);   // counters + cntg
    hipMemsetAsync(feat0f, 0, (size_t)CAP0 * 128 * 4, stream);
    hipMemsetAsync(dout, 0, (size_t)out_size * 4, stream);

    // ---- constants (one fused launch) ----
    k_prep<<<(PREP_TOT + 255)/256, 256, 0, stream>>>(w1, w2, w3, wd1, wd2,
        B1, B2, B3, Bd1, Bd2, bng, bnb, bnm, bnv, bnscale, bnshift);

    // ---- sparse structure ----
    k_count<<<(NV_ + 255)/256, 256, 0, stream>>>(coors, cntg);
    k_compact0<<<(NCELL0 + 255)/256, 256, 0, stream>>>(cntg, idx0, list0, counters + 0);
    k_scatter<<<(NV_*32 + 255)/256, 256, 0, stream>>>(vf, coors, cntg, idx0, feat0f);
    k_convert<<<(CAP0*16 + 255)/256, 256, 0, stream>>>(feat0f, feat0b, counters + 0);
    k_compact_dn<<<(NCELL1 + 255)/256, 256, 0, stream>>>(idx0, idx1, list1, counters + 1, NCELL1);
    k_compact_dn<<<(NCELL2 + 255)/256, 256, 0, stream>>>(idx1, idx2, list2, counters + 2, NCELL2);

    dim3 gn((CAP1*27 + 255)/256, 4);
    k_nbrs<<<gn, 256, 0, stream>>>(list0, list1, list2, idx0, idx1,
                                   nbr0, nbr1, dnb1, dnb2, counters);

    // ---- the five gather-GEMMs ----
    k_gemm<27,false><<<CAP0/64, 256, 0, stream>>>((const int4*)feat0b, nbr0, B1, feat1,
        counters + 0, bnscale + 0,   bnshift + 0,   nullptr, nullptr);
    k_gemm<3,false><<<CAP1/64, 256, 0, stream>>>((const int4*)feat1, dnb1, Bd1, featd1,
        counters + 1, bnscale + 64,  bnshift + 64,  nullptr, nullptr);
    k_gemm<27,false><<<CAP1/64, 256, 0, stream>>>((const int4*)featd1, nbr1, B2, feat2,
        counters + 1, bnscale + 128, bnshift + 128, nullptr, nullptr);
    k_gemm<27,false><<<CAP1/64, 256, 0, stream>>>((const int4*)feat2, nbr1, B3, feat3,
        counters + 1, bnscale + 192, bnshift + 192, nullptr, nullptr);
    k_gemm<3,true><<<CAP2/64, 256, 0, stream>>>((const int4*)feat3, dnb2, Bd2, nullptr,
        counters + 2, bnscale + 256, bnshift + 256, list2, dout);
}

// Round 7
// 404.195 us; speedup vs baseline: 2.0368x; 1.1138x over previous
//
#include <hip/hip_runtime.h>

typedef float floatx4 __attribute__((ext_vector_type(4)));
typedef __bf16 bf16x8 __attribute__((ext_vector_type(8)));

#define D0_ 19
#define H0_ 200
#define W0_ 176
#define HW_ (H0_*W0_)          // 35200
#define NCELL0 (D0_*HW_)       // 668800
#define D1_ 9
#define NCELL1 (D1_*HW_)       // 316800
#define D2_ 4
#define NCELL2 (D2_*HW_)       // 140800
#define NV_ 40000
#define CAP0 40000
#define CAP1 80000
#define CAP2 140800
#define EPS_ 1e-3f

__device__ __forceinline__ float bf2f(short s){
    union { unsigned u; float f; } x; x.u = ((unsigned)(unsigned short)s) << 16; return x.f;
}
__device__ __forceinline__ short f2bf(float f){
    union { float f; unsigned u; } x; x.f = f;
    unsigned r = x.u + 0x7fffu + ((x.u >> 16) & 1u);
    return (short)(r >> 16);
}

// ---------------- fused constant prep: BN consts + 5 weight repacks ----------------
// repack dest: Bout[ ((kchunk*4 + ntile)*64 + lane)*8 + jj ], lane = ((k>>3)&3)*16 + (n&15)
__device__ __forceinline__ void repack_one(const float* w, short* Bout, int i, int KCsrc, int NSP){
    int k = i >> 6, n = i & 63;
    int ci = k & 127;
    int cis = (KCsrc == 128) ? ci : (ci & 63);
    short val = f2bf(w[(n * KCsrc + cis) * NSP + (k >> 7)]);
    int kc = k >> 5, lanehi = (k >> 3) & 3, jj = k & 7;
    int nt = n >> 4, lane = lanehi * 16 + (n & 15);
    Bout[((kc * 4 + nt) * 64 + lane) * 8 + jj] = val;
}

#define RP_BIG (3456*64)   // 221184
#define RP_SML (384*64)    // 24576

__global__ void k_prep(const float* w1, const float* w2, const float* w3,
                       const float* wd1, const float* wd2,
                       short* B1, short* B2, short* B3, short* Bd1, short* Bd2,
                       const float* g, const float* b, const float* m, const float* v,
                       float* scale, float* shift){
    int i = blockIdx.x * 256 + threadIdx.x;
    if (i < RP_BIG){ repack_one(w1, B1, i, 128, 27); return; }
    i -= RP_BIG;
    if (i < RP_BIG){ repack_one(w2, B2, i, 64, 27); return; }
    i -= RP_BIG;
    if (i < RP_BIG){ repack_one(w3, B3, i, 64, 27); return; }
    i -= RP_BIG;
    if (i < RP_SML){ repack_one(wd1, Bd1, i, 64, 3); return; }
    i -= RP_SML;
    if (i < RP_SML){ repack_one(wd2, Bd2, i, 64, 3); return; }
    i -= RP_SML;
    if (i < 5*64){
        float s = g[i] / sqrtf(v[i] + EPS_);
        scale[i] = s;
        shift[i] = b[i] - m[i] * s;
    }
}
#define PREP_TOT (3*RP_BIG + 2*RP_SML + 5*64)

// ---------------- voxel count per cell (distinct addresses - fine) ----------------
__global__ void k_count(const int* coors, int* cntg){
    int v = blockIdx.x * 256 + threadIdx.x;
    if (v >= NV_) return;
    int z = coors[v*4+1], y = coors[v*4+2], x = coors[v*4+3];
    atomicAdd(&cntg[(z*H0_ + y)*W0_ + x], 1);
}

// ---------------- block-aggregated row assignment: ONE atomic per block ----------------
__device__ __forceinline__ int blk_rank(bool act, int* cnt, int& r_out){
    unsigned long long mask = __ballot(act);
    int lane = threadIdx.x & 63, wid = threadIdx.x >> 6;
    int wrank = __popcll(mask & ((1ull << lane) - 1));
    __shared__ int ws[4];
    __shared__ int blkbase;
    if (lane == 0) ws[wid] = __popcll(mask);
    __syncthreads();
    if (threadIdx.x == 0){
        int t0 = ws[0], t1 = ws[1], t2 = ws[2], t3 = ws[3];
        int tot = t0 + t1 + t2 + t3;
        blkbase = tot ? atomicAdd(cnt, tot) : 0;
        ws[0] = 0; ws[1] = t0; ws[2] = t0 + t1; ws[3] = t0 + t1 + t2;
    }
    __syncthreads();
    r_out = blkbase + ws[wid] + wrank;
    return 0;
}

// ---------------- compact level 0 ----------------
__global__ void k_compact0(const int* cntg, int* idx0, int* list0, int* cnt0){
    int c = blockIdx.x * 256 + threadIdx.x;
    bool act = (c < NCELL0) && (cntg[c] > 0);
    int r; blk_rank(act, cnt0, r);
    if (c >= NCELL0) return;
    if (act){
        idx0[c] = r;
        int z = c / HW_; int rem = c - z * HW_;
        int y = rem / W0_; int x = rem - y * W0_;
        list0[r] = (z << 16) | (y << 8) | x;
    } else idx0[c] = -1;
}

// ---------------- compact level 1/2 (stride-2 depth pooling of parent idx grid) ----------------
__global__ void k_compact_dn(const int* idxsrc, int* idxdst, int* listdst, int* cnt,
                             int ncell){
    int c = blockIdx.x * 256 + threadIdx.x;
    bool act = false;
    int d = 0, y = 0, x = 0;
    if (c < ncell){
        d = c / HW_; int rem = c - d * HW_;
        y = rem / W0_; x = rem - y * W0_;
        #pragma unroll
        for (int j = 0; j < 3; ++j)
            act = act || (idxsrc[((2*d + j)*H0_ + y)*W0_ + x] >= 0);
    }
    int r; blk_rank(act, cnt, r);
    if (c >= ncell) return;
    if (act){
        idxdst[c] = r;
        listdst[r] = (d << 16) | (y << 8) | x;
    } else idxdst[c] = -1;
}

// ---------------- scatter fp32 features: 32 threads/voxel, fast path for unique cells ----------------
__global__ void k_scatter(const float* vf, const int* coors, const int* cntg,
                          const int* idx0, float* feat0f){
    int u = blockIdx.x * 256 + threadIdx.x;
    if (u >= NV_ * 32) return;
    int v = u >> 5, c4 = u & 31;             // 32 threads x float4 = 128 channels
    int z = coors[v*4+1], y = coors[v*4+2], x = coors[v*4+3];
    int cell = (z*H0_ + y)*W0_ + x;
    int row = idx0[cell];
    float4 s = ((const float4*)(vf + (long)v * 128))[c4];
    float* dst = feat0f + (long)row * 128 + c4 * 4;
    if (cntg[cell] == 1){
        *(float4*)dst = s;
    } else {
        atomicAdd(dst+0, s.x); atomicAdd(dst+1, s.y);
        atomicAdd(dst+2, s.z); atomicAdd(dst+3, s.w);
    }
}

// ---------------- fp32 -> bf16 convert (8 per thread) ----------------
__global__ void k_convert(const float* f, short* b, const int* cntp){
    int n8 = cntp[0] * 16;
    int i = blockIdx.x * 256 + threadIdx.x;
    if (i >= n8) return;
    float4 a = ((const float4*)f)[i*2], c = ((const float4*)f)[i*2+1];
    short o[8] = { f2bf(a.x), f2bf(a.y), f2bf(a.z), f2bf(a.w),
                   f2bf(c.x), f2bf(c.y), f2bf(c.z), f2bf(c.w) };
    ((int4*)b)[i] = *(int4*)o;
}

// ---------------- fused neighbor tables (coalesced u = site*NT + j) ----------------
__global__ void k_nbrs(const int* list0, const int* list1, const int* list2,
                       const int* idx0, const int* idx1,
                       int* nbr0, int* nbr1, int* dnb1, int* dnb2,
                       const int* counters){
    int job = blockIdx.y;
    int u = blockIdx.x * 256 + threadIdx.x;
    if (job <= 1){
        int M = counters[job];
        if (u >= M * 27) return;
        int site = u / 27, j = u - site * 27;
        const int* list = job ? list1 : list0;
        const int* idxg = job ? idx1 : idx0;
        int Dd = job ? D1_ : D0_;
        int cell = list[site];
        int z = cell >> 16, y = (cell >> 8) & 255, x = cell & 255;
        int nz = z + j/9 - 1, ny = y + (j/3)%3 - 1, nx = x + j%3 - 1;
        int r = -1;
        if ((unsigned)nz < (unsigned)Dd && (unsigned)ny < H0_ && (unsigned)nx < W0_)
            r = idxg[(nz*H0_ + ny)*W0_ + nx];
        (job ? nbr1 : nbr0)[u] = r;
    } else {
        int M = counters[job - 1];
        if (u >= M * 3) return;
        int site = u / 3, j = u - site * 3;
        const int* list = (job == 2) ? list1 : list2;
        const int* idxg = (job == 2) ? idx0 : idx1;
        int cell = list[site];
        int d = cell >> 16, y = (cell >> 8) & 255, x = cell & 255;
        (job == 2 ? dnb1 : dnb2)[u] = idxg[((2*d + j)*H0_ + y)*W0_ + x];
    }
}

// ---------------- gather-GEMM, LDS-free: C[M x 64] = gatherA[M x NNBR*128] @ B ----------------
// M-tile 128/block; each wave owns row-groups rg=wave and rg=wave+4 (16 rows each).
// A gathered straight into registers (row stride = 128 shorts!); B fragments from L1/L2;
// 16 B-loads feed 32 MFMAs per tap. No LDS, no barriers -> waves fully independent.
template<int NNBR, bool FINAL>
__global__ __launch_bounds__(256) void k_gemm(
    const short* __restrict__ featA, const int* __restrict__ nbr,
    const short* __restrict__ Bs, short* __restrict__ out,
    const int* __restrict__ cntp,
    const float* __restrict__ scale, const float* __restrict__ shift,
    const int* __restrict__ list, float* __restrict__ dout)
{
    int M = *cntp;
    int m0 = blockIdx.x * 128;
    if (m0 >= M) return;
    int tid = threadIdx.x;
    int wave = tid >> 6, lane = tid & 63;
    int m16 = lane & 15;
    int koff = (lane >> 4) * 8;              // short offset of this lane's 8-elem k-slice

    int row0 = m0 + wave * 16 + m16;         // rg = wave
    int row1 = row0 + 64;                    // rg = wave + 4
    bool ok0 = row0 < M, ok1 = row1 < M;
    const int* np0 = nbr + (long)row0 * NNBR;
    const int* np1 = nbr + (long)row1 * NNBR;
    const short* Bl = Bs + (long)lane * 8;   // frag t at Bl + t*512

    floatx4 acc0[4] = {}, acc1[4] = {};

    for (int j = 0; j < NNBR; ++j){
        int r0 = ok0 ? np0[j] : -1;
        int r1 = ok1 ? np1[j] : -1;
        bf16x8 a0[4] = {{0,0,0,0,0,0,0,0}, {0,0,0,0,0,0,0,0}, {0,0,0,0,0,0,0,0}, {0,0,0,0,0,0,0,0}};
        bf16x8 a1[4] = {{0,0,0,0,0,0,0,0}, {0,0,0,0,0,0,0,0}, {0,0,0,0,0,0,0,0}, {0,0,0,0,0,0,0,0}};
        if (r0 >= 0){
            const short* b0 = featA + (long)r0 * 128 + koff;     // row stride = 128 shorts
            #pragma unroll
            for (int kc = 0; kc < 4; ++kc) a0[kc] = *(const bf16x8*)(b0 + kc*32);
        }
        if (r1 >= 0){
            const short* b1 = featA + (long)r1 * 128 + koff;     // row stride = 128 shorts
            #pragma unroll
            for (int kc = 0; kc < 4; ++kc) a1[kc] = *(const bf16x8*)(b1 + kc*32);
        }
        const short* Bj = Bl + (long)j * 16 * 512;
        #pragma unroll
        for (int kc = 0; kc < 4; ++kc){
            bf16x8 b[4];
            #pragma unroll
            for (int nt = 0; nt < 4; ++nt) b[nt] = *(const bf16x8*)(Bj + (kc*4 + nt) * 512);
            #pragma unroll
            for (int nt = 0; nt < 4; ++nt)
                acc0[nt] = __builtin_amdgcn_mfma_f32_16x16x32_bf16(a0[kc], b[nt], acc0[nt], 0, 0, 0);
            #pragma unroll
            for (int nt = 0; nt < 4; ++nt)
                acc1[nt] = __builtin_amdgcn_mfma_f32_16x16x32_bf16(a1[kc], b[nt], acc1[nt], 0, 0, 0);
        }
    }

    // epilogue: C/D layout col = lane&15, row = (lane>>4)*4 + reg
    int n16 = lane & 15;
    #pragma unroll
    for (int rg = 0; rg < 2; ++rg){
        const floatx4* ac = rg ? acc1 : acc0;
        int mb = m0 + (wave + rg*4) * 16 + (lane >> 4) * 4;
        #pragma unroll
        for (int nt = 0; nt < 4; ++nt){
            int n = nt * 16 + n16;
            float sc = scale[n], sh = shift[n];
            #pragma unroll
            for (int r = 0; r < 4; ++r){
                int site = mb + r;
                if (site < M){
                    float y = fmaxf(ac[nt][r] * sc + sh, 0.f);
                    if (FINAL){
                        int cell = list[site];
                        int d = cell >> 16, yy = (cell >> 8) & 255, xx = cell & 255;
                        dout[((n*4 + d)*H0_ + yy)*W0_ + xx] = y;
                    } else {
                        short hi = f2bf(y);
                        float lo = y - bf2f(hi);
                        out[(long)site*128 + n]      = hi;
                        out[(long)site*128 + 64 + n] = f2bf(lo);
                    }
                }
            }
        }
    }
}

extern "C" void kernel_launch(void* const* d_in, const int* in_sizes, int n_in,
                              void* d_out, int out_size, void* d_ws, size_t ws_size,
                              hipStream_t stream){
    const float* vf   = (const float*)d_in[0];
    const int*   coors= (const int*)  d_in[1];
    const float* w1   = (const float*)d_in[3];
    const float* wd1  = (const float*)d_in[4];
    const float* w2   = (const float*)d_in[5];
    const float* w3   = (const float*)d_in[6];
    const float* wd2  = (const float*)d_in[7];
    const float* bng  = (const float*)d_in[8];
    const float* bnb  = (const float*)d_in[9];
    const float* bnm  = (const float*)d_in[10];
    const float* bnv  = (const float*)d_in[11];
    float* dout = (float*)d_out;

    char* ws = (char*)d_ws;
    size_t off = 0;
    auto alloc = [&](size_t bytes)->char* {
        char* p = ws + off;
        off += (bytes + 255) & ~(size_t)255;
        return p;
    };

    int*   counters = (int*)  alloc(256);                    // [0]=cnt0 [1]=cnt1 [2]=cnt2
    int*   cntg     = (int*)  alloc((size_t)NCELL0 * 4);     // contiguous after counters
    int*   idx0     = (int*)  alloc((size_t)NCELL0 * 4);
    int*   idx1     = (int*)  alloc((size_t)NCELL1 * 4);
    int*   idx2     = (int*)  alloc((size_t)NCELL2 * 4);
    int*   list0    = (int*)  alloc((size_t)CAP0 * 4);
    int*   list1    = (int*)  alloc((size_t)CAP1 * 4);
    int*   list2    = (int*)  alloc((size_t)CAP2 * 4);
    float* feat0f   = (float*)alloc((size_t)CAP0 * 128 * 4); // fp32 scatter accum; feat2 aliases later
    short* feat0b   = (short*)alloc((size_t)CAP0 * 128 * 2);
    short* feat1    = (short*)alloc((size_t)CAP0 * 128 * 2);
    short* featd1   = (short*)alloc((size_t)CAP1 * 128 * 2);
    short* feat3    = (short*)alloc((size_t)CAP1 * 128 * 2);
    int*   nbr0     = (int*)  alloc((size_t)CAP0 * 27 * 4);
    int*   nbr1     = (int*)  alloc((size_t)CAP1 * 27 * 4);
    int*   dnb1     = (int*)  alloc((size_t)CAP1 * 3 * 4);
    int*   dnb2     = (int*)  alloc((size_t)CAP2 * 3 * 4);
    short* B1  = (short*)alloc((size_t)3456 * 64 * 2);
    short* B2  = (short*)alloc((size_t)3456 * 64 * 2);
    short* B3  = (short*)alloc((size_t)3456 * 64 * 2);
    short* Bd1 = (short*)alloc((size_t)384 * 64 * 2);
    short* Bd2 = (short*)alloc((size_t)384 * 64 * 2);
    float* bnscale = (float*)alloc(5 * 64 * 4);
    float* bnshift = (float*)alloc(5 * 64 * 4);
    short* feat2 = (short*)feat0f;   // alias: feat0f dead after k_convert

    // ---- zero (ws/d_out poisoned 0xAA) ----
    hipMemsetAsync(counters, 0, 256 + (size_t)NCELL0 * 4, stream);   // counters + cntg
    hipMemsetAsync(feat0f, 0, (size_t)CAP0 * 128 * 4, stream);
    hipMemsetAsync(dout, 0, (size_t)out_size * 4, stream);

    // ---- constants (one fused launch) ----
    k_prep<<<(PREP_TOT + 255)/256, 256, 0, stream>>>(w1, w2, w3, wd1, wd2,
        B1, B2, B3, Bd1, Bd2, bng, bnb, bnm, bnv, bnscale, bnshift);

    // ---- sparse structure ----
    k_count<<<(NV_ + 255)/256, 256, 0, stream>>>(coors, cntg);
    k_compact0<<<(NCELL0 + 255)/256, 256, 0, stream>>>(cntg, idx0, list0, counters + 0);
    k_scatter<<<(NV_*32 + 255)/256, 256, 0, stream>>>(vf, coors, cntg, idx0, feat0f);
    k_convert<<<(CAP0*16 + 255)/256, 256, 0, stream>>>(feat0f, feat0b, counters + 0);
    k_compact_dn<<<(NCELL1 + 255)/256, 256, 0, stream>>>(idx0, idx1, list1, counters + 1, NCELL1);
    k_compact_dn<<<(NCELL2 + 255)/256, 256, 0, stream>>>(idx1, idx2, list2, counters + 2, NCELL2);

    dim3 gn((CAP1*27 + 255)/256, 4);
    k_nbrs<<<gn, 256, 0, stream>>>(list0, list1, list2, idx0, idx1,
                                   nbr0, nbr1, dnb1, dnb2, counters);

    // ---- the five gather-GEMMs (M-tile 128) ----
    k_gemm<27,false><<<(CAP0+127)/128, 256, 0, stream>>>(feat0b, nbr0, B1, feat1,
        counters + 0, bnscale + 0,   bnshift + 0,   nullptr, nullptr);
    k_gemm<3,false><<<(CAP1+127)/128, 256, 0, stream>>>(feat1, dnb1, Bd1, featd1,
        counters + 1, bnscale + 64,  bnshift + 64,  nullptr, nullptr);
    k_gemm<27,false><<<(CAP1+127)/128, 256, 0, stream>>>(featd1, nbr1, B2, feat2,
        counters + 1, bnscale + 128, bnshift + 128, nullptr, nullptr);
    k_gemm<27,false><<<(CAP1+127)/128, 256, 0, stream>>>(feat2, nbr1, B3, feat3,
        counters + 1, bnscale + 192, bnshift + 192, nullptr, nullptr);
    k_gemm<3,true><<<(CAP2+127)/128, 256, 0, stream>>>(feat3, dnb2, Bd2, nullptr,
        counters + 2, bnscale + 256, bnshift + 256, list2, dout);
}

// Round 8
// 383.045 us; speedup vs baseline: 2.1492x; 1.0552x over previous
//
#include <hip/hip_runtime.h>

typedef float floatx4 __attribute__((ext_vector_type(4)));
typedef __bf16 bf16x8 __attribute__((ext_vector_type(8)));

#define D0_ 19
#define H0_ 200
#define W0_ 176
#define HW_ (H0_*W0_)          // 35200
#define NCELL0 (D0_*HW_)       // 668800
#define D1_ 9
#define NCELL1 (D1_*HW_)       // 316800
#define D2_ 4
#define NCELL2 (D2_*HW_)       // 140800
#define NV_ 40000
#define CAP0 40000
#define CAP1 80000
#define CAP2 140800
#define EPS_ 1e-3f

__device__ __forceinline__ float bf2f(short s){
    union { unsigned u; float f; } x; x.u = ((unsigned)(unsigned short)s) << 16; return x.f;
}
__device__ __forceinline__ short f2bf(float f){
    union { float f; unsigned u; } x; x.f = f;
    unsigned r = x.u + 0x7fffu + ((x.u >> 16) & 1u);
    return (short)(r >> 16);
}

// ---------------- fused constant prep: BN consts + 5 weight repacks ----------------
__device__ __forceinline__ void repack_one(const float* w, short* Bout, int i, int KCsrc, int NSP){
    int k = i >> 6, n = i & 63;
    int ci = k & 127;
    int cis = (KCsrc == 128) ? ci : (ci & 63);
    short val = f2bf(w[(n * KCsrc + cis) * NSP + (k >> 7)]);
    int kc = k >> 5, lanehi = (k >> 3) & 3, jj = k & 7;
    int nt = n >> 4, lane = lanehi * 16 + (n & 15);
    Bout[((kc * 4 + nt) * 64 + lane) * 8 + jj] = val;
}

#define RP_BIG (3456*64)   // 221184
#define RP_SML (384*64)    // 24576

__global__ void k_prep(const float* w1, const float* w2, const float* w3,
                       const float* wd1, const float* wd2,
                       short* B1, short* B2, short* B3, short* Bd1, short* Bd2,
                       const float* g, const float* b, const float* m, const float* v,
                       float* scale, float* shift){
    int i = blockIdx.x * 256 + threadIdx.x;
    if (i < RP_BIG){ repack_one(w1, B1, i, 128, 27); return; }
    i -= RP_BIG;
    if (i < RP_BIG){ repack_one(w2, B2, i, 64, 27); return; }
    i -= RP_BIG;
    if (i < RP_BIG){ repack_one(w3, B3, i, 64, 27); return; }
    i -= RP_BIG;
    if (i < RP_SML){ repack_one(wd1, Bd1, i, 64, 3); return; }
    i -= RP_SML;
    if (i < RP_SML){ repack_one(wd2, Bd2, i, 64, 3); return; }
    i -= RP_SML;
    if (i < 5*64){
        float s = g[i] / sqrtf(v[i] + EPS_);
        scale[i] = s;
        shift[i] = b[i] - m[i] * s;
    }
}
#define PREP_TOT (3*RP_BIG + 2*RP_SML + 5*64)

// ---------------- voxel count per cell ----------------
__global__ void k_count(const int* coors, int* cntg){
    int v = blockIdx.x * 256 + threadIdx.x;
    if (v >= NV_) return;
    int z = coors[v*4+1], y = coors[v*4+2], x = coors[v*4+3];
    atomicAdd(&cntg[(z*H0_ + y)*W0_ + x], 1);
}

// ---------------- block-aggregated row assignment: ONE atomic per block ----------------
__device__ __forceinline__ int blk_rank(bool act, int* cnt, int& r_out){
    unsigned long long mask = __ballot(act);
    int lane = threadIdx.x & 63, wid = threadIdx.x >> 6;
    int wrank = __popcll(mask & ((1ull << lane) - 1));
    __shared__ int ws[4];
    __shared__ int blkbase;
    if (lane == 0) ws[wid] = __popcll(mask);
    __syncthreads();
    if (threadIdx.x == 0){
        int t0 = ws[0], t1 = ws[1], t2 = ws[2], t3 = ws[3];
        int tot = t0 + t1 + t2 + t3;
        blkbase = tot ? atomicAdd(cnt, tot) : 0;
        ws[0] = 0; ws[1] = t0; ws[2] = t0 + t1; ws[3] = t0 + t1 + t2;
    }
    __syncthreads();
    r_out = blkbase + ws[wid] + wrank;
    return 0;
}

// ---------------- compact level 0 ----------------
__global__ void k_compact0(const int* cntg, int* idx0, int* list0, int* cnt0){
    int c = blockIdx.x * 256 + threadIdx.x;
    bool act = (c < NCELL0) && (cntg[c] > 0);
    int r; blk_rank(act, cnt0, r);
    if (c >= NCELL0) return;
    if (act){
        idx0[c] = r;
        int z = c / HW_; int rem = c - z * HW_;
        int y = rem / W0_; int x = rem - y * W0_;
        list0[r] = (z << 16) | (y << 8) | x;
    } else idx0[c] = -1;
}

// ---------------- compact level 1/2 ----------------
__global__ void k_compact_dn(const int* idxsrc, int* idxdst, int* listdst, int* cnt,
                             int ncell){
    int c = blockIdx.x * 256 + threadIdx.x;
    bool act = false;
    int d = 0, y = 0, x = 0;
    if (c < ncell){
        d = c / HW_; int rem = c - d * HW_;
        y = rem / W0_; x = rem - y * W0_;
        #pragma unroll
        for (int j = 0; j < 3; ++j)
            act = act || (idxsrc[((2*d + j)*H0_ + y)*W0_ + x] >= 0);
    }
    int r; blk_rank(act, cnt, r);
    if (c >= ncell) return;
    if (act){
        idxdst[c] = r;
        listdst[r] = (d << 16) | (y << 8) | x;
    } else idxdst[c] = -1;
}

// ---------------- scatter fp32 features ----------------
__global__ void k_scatter(const float* vf, const int* coors, const int* cntg,
                          const int* idx0, float* feat0f){
    int u = blockIdx.x * 256 + threadIdx.x;
    if (u >= NV_ * 32) return;
    int v = u >> 5, c4 = u & 31;
    int z = coors[v*4+1], y = coors[v*4+2], x = coors[v*4+3];
    int cell = (z*H0_ + y)*W0_ + x;
    int row = idx0[cell];
    float4 s = ((const float4*)(vf + (long)v * 128))[c4];
    float* dst = feat0f + (long)row * 128 + c4 * 4;
    if (cntg[cell] == 1){
        *(float4*)dst = s;
    } else {
        atomicAdd(dst+0, s.x); atomicAdd(dst+1, s.y);
        atomicAdd(dst+2, s.z); atomicAdd(dst+3, s.w);
    }
}

// ---------------- fp32 -> bf16 convert ----------------
__global__ void k_convert(const float* f, short* b, const int* cntp){
    int n8 = cntp[0] * 16;
    int i = blockIdx.x * 256 + threadIdx.x;
    if (i >= n8) return;
    float4 a = ((const float4*)f)[i*2], c = ((const float4*)f)[i*2+1];
    short o[8] = { f2bf(a.x), f2bf(a.y), f2bf(a.z), f2bf(a.w),
                   f2bf(c.x), f2bf(c.y), f2bf(c.z), f2bf(c.w) };
    ((int4*)b)[i] = *(int4*)o;
}

// ---------------- transposed 27-tap neighbor tables: nbrT[j*cap + site] ----------------
__global__ void k_nbr27(const int* list0, const int* list1,
                        const int* idx0, const int* idx1,
                        int* nbr0T, int* nbr1T, const int* counters){
    int lvl = blockIdx.z;
    int j = blockIdx.y;
    int site = blockIdx.x * 256 + threadIdx.x;
    int M = counters[lvl];
    if (site >= M) return;
    const int* list = lvl ? list1 : list0;
    const int* idxg = lvl ? idx1 : idx0;
    int Dd = lvl ? D1_ : D0_;
    int cap = lvl ? CAP1 : CAP0;
    int cell = list[site];
    int z = cell >> 16, y = (cell >> 8) & 255, x = cell & 255;
    int nz = z + j/9 - 1, ny = y + (j/3)%3 - 1, nx = x + j%3 - 1;
    int r = -1;
    if ((unsigned)nz < (unsigned)Dd && (unsigned)ny < H0_ && (unsigned)nx < W0_)
        r = idxg[(nz*H0_ + ny)*W0_ + nx];
    (lvl ? nbr1T : nbr0T)[j * cap + site] = r;
}

// ---------------- transposed 3-tap downsample tables ----------------
__global__ void k_nbr3(const int* list1, const int* list2,
                       const int* idx0, const int* idx1,
                       int* dnb1T, int* dnb2T, const int* counters){
    int lvl = blockIdx.z;                // 0: dn1, 1: dn2
    int j = blockIdx.y;
    int site = blockIdx.x * 256 + threadIdx.x;
    int M = counters[lvl + 1];
    if (site >= M) return;
    const int* list = lvl ? list2 : list1;
    const int* idxg = lvl ? idx1 : idx0;
    int cap = lvl ? CAP2 : CAP1;
    int cell = list[site];
    int d = cell >> 16, y = (cell >> 8) & 255, x = cell & 255;
    (lvl ? dnb2T : dnb1T)[j * cap + site] = idxg[((2*d + j)*H0_ + y)*W0_ + x];
}

// ---------------- gather-GEMM, LDS-free, software-pipelined ----------------
// M-tile 128/block; wave owns row-groups wave and wave+4. nbr prefetched 2 taps
// ahead, A fragments double-buffered 1 tap ahead; B fragments from L1/L2.
template<int NNBR, bool FINAL>
__global__ __launch_bounds__(256) void k_gemm(
    const short* __restrict__ featA, const int* __restrict__ nbrT, int nstride,
    const short* __restrict__ Bs, short* __restrict__ out,
    const int* __restrict__ cntp,
    const float* __restrict__ scale, const float* __restrict__ shift,
    const int* __restrict__ list, float* __restrict__ dout)
{
    int M = *cntp;
    int m0 = blockIdx.x * 128;
    if (m0 >= M) return;
    int tid = threadIdx.x;
    int wave = tid >> 6, lane = tid & 63;
    int m16 = lane & 15;
    int koff = (lane >> 4) * 8;

    int row0 = m0 + wave * 16 + m16;
    int row1 = row0 + 64;
    bool ok0 = row0 < M, ok1 = row1 < M;
    const short* Bl = Bs + (long)lane * 8;

    floatx4 acc0[4] = {}, acc1[4] = {};
    bf16x8 pf0[2][4], pf1[2][4];

    auto loadA = [&](bf16x8* d, int r){
        if (r >= 0){
            const short* p = featA + (long)r * 128 + koff;
            #pragma unroll
            for (int kc = 0; kc < 4; ++kc) d[kc] = *(const bf16x8*)(p + kc*32);
        } else {
            #pragma unroll
            for (int kc = 0; kc < 4; ++kc) d[kc] = (bf16x8){0,0,0,0,0,0,0,0};
        }
    };

    // prologue: tap0 A in flight, tap1 nbr in flight
    int rc0 = ok0 ? nbrT[row0] : -1;
    int rc1 = ok1 ? nbrT[row1] : -1;
    loadA(pf0[0], rc0); loadA(pf1[0], rc1);
    int rb0 = (NNBR > 1 && ok0) ? nbrT[nstride + row0] : -1;
    int rb1 = (NNBR > 1 && ok1) ? nbrT[nstride + row1] : -1;
    int ra0 = -1, ra1 = -1;

    #pragma unroll
    for (int j = 0; j < NNBR; ++j){
        if (j + 1 < NNBR){                 // A prefetch for tap j+1
            loadA(pf0[(j+1)&1], rb0);
            loadA(pf1[(j+1)&1], rb1);
        }
        if (j + 2 < NNBR){                 // nbr prefetch for tap j+2
            ra0 = ok0 ? nbrT[(j+2)*nstride + row0] : -1;
            ra1 = ok1 ? nbrT[(j+2)*nstride + row1] : -1;
        }
        const bf16x8* a0 = pf0[j & 1];
        const bf16x8* a1 = pf1[j & 1];
        const short* Bj = Bl + (long)j * 16 * 512;
        #pragma unroll
        for (int kc = 0; kc < 4; ++kc){
            bf16x8 b[4];
            #pragma unroll
            for (int nt = 0; nt < 4; ++nt) b[nt] = *(const bf16x8*)(Bj + (kc*4 + nt) * 512);
            #pragma unroll
            for (int nt = 0; nt < 4; ++nt)
                acc0[nt] = __builtin_amdgcn_mfma_f32_16x16x32_bf16(a0[kc], b[nt], acc0[nt], 0, 0, 0);
            #pragma unroll
            for (int nt = 0; nt < 4; ++nt)
                acc1[nt] = __builtin_amdgcn_mfma_f32_16x16x32_bf16(a1[kc], b[nt], acc1[nt], 0, 0, 0);
        }
        rb0 = ra0; rb1 = ra1;
    }

    // epilogue: C/D layout col = lane&15, row = (lane>>4)*4 + reg
    int n16 = lane & 15;
    #pragma unroll
    for (int rg = 0; rg < 2; ++rg){
        const floatx4* ac = rg ? acc1 : acc0;
        int mb = m0 + (wave + rg*4) * 16 + (lane >> 4) * 4;
        #pragma unroll
        for (int nt = 0; nt < 4; ++nt){
            int n = nt * 16 + n16;
            float sc = scale[n], sh = shift[n];
            #pragma unroll
            for (int r = 0; r < 4; ++r){
                int site = mb + r;
                if (site < M){
                    float y = fmaxf(ac[nt][r] * sc + sh, 0.f);
                    if (FINAL){
                        int cell = list[site];
                        int d = cell >> 16, yy = (cell >> 8) & 255, xx = cell & 255;
                        dout[((n*4 + d)*H0_ + yy)*W0_ + xx] = y;
                    } else {
                        short hi = f2bf(y);
                        float lo = y - bf2f(hi);
                        out[(long)site*128 + n]      = hi;
                        out[(long)site*128 + 64 + n] = f2bf(lo);
                    }
                }
            }
        }
    }
}

extern "C" void kernel_launch(void* const* d_in, const int* in_sizes, int n_in,
                              void* d_out, int out_size, void* d_ws, size_t ws_size,
                              hipStream_t stream){
    const float* vf   = (const float*)d_in[0];
    const int*   coors= (const int*)  d_in[1];
    const float* w1   = (const float*)d_in[3];
    const float* wd1  = (const float*)d_in[4];
    const float* w2   = (const float*)d_in[5];
    const float* w3   = (const float*)d_in[6];
    const float* wd2  = (const float*)d_in[7];
    const float* bng  = (const float*)d_in[8];
    const float* bnb  = (const float*)d_in[9];
    const float* bnm  = (const float*)d_in[10];
    const float* bnv  = (const float*)d_in[11];
    float* dout = (float*)d_out;

    char* ws = (char*)d_ws;
    size_t off = 0;
    auto alloc = [&](size_t bytes)->char* {
        char* p = ws + off;
        off += (bytes + 255) & ~(size_t)255;
        return p;
    };

    int*   counters = (int*)  alloc(256);                    // [0]=cnt0 [1]=cnt1 [2]=cnt2
    int*   cntg     = (int*)  alloc((size_t)NCELL0 * 4);
    int*   idx0     = (int*)  alloc((size_t)NCELL0 * 4);
    int*   idx1     = (int*)  alloc((size_t)NCELL1 * 4);
    int*   idx2     = (int*)  alloc((size_t)NCELL2 * 4);
    int*   list0    = (int*)  alloc((size_t)CAP0 * 4);
    int*   list1    = (int*)  alloc((size_t)CAP1 * 4);
    int*   list2    = (int*)  alloc((size_t)CAP2 * 4);
    float* feat0f   = (float*)alloc((size_t)CAP0 * 128 * 4);
    short* feat0b   = (short*)alloc((size_t)CAP0 * 128 * 2);
    short* feat1    = (short*)alloc((size_t)CAP0 * 128 * 2);
    short* featd1   = (short*)alloc((size_t)CAP1 * 128 * 2);
    short* feat3    = (short*)alloc((size_t)CAP1 * 128 * 2);
    int*   nbr0T    = (int*)  alloc((size_t)CAP0 * 27 * 4);
    int*   nbr1T    = (int*)  alloc((size_t)CAP1 * 27 * 4);
    int*   dnb1T    = (int*)  alloc((size_t)CAP1 * 3 * 4);
    int*   dnb2T    = (int*)  alloc((size_t)CAP2 * 3 * 4);
    short* B1  = (short*)alloc((size_t)3456 * 64 * 2);
    short* B2  = (short*)alloc((size_t)3456 * 64 * 2);
    short* B3  = (short*)alloc((size_t)3456 * 64 * 2);
    short* Bd1 = (short*)alloc((size_t)384 * 64 * 2);
    short* Bd2 = (short*)alloc((size_t)384 * 64 * 2);
    float* bnscale = (float*)alloc(5 * 64 * 4);
    float* bnshift = (float*)alloc(5 * 64 * 4);
    short* feat2 = (short*)feat0f;   // alias: feat0f dead after k_convert

    // ---- zero (ws/d_out poisoned 0xAA) ----
    hipMemsetAsync(counters, 0, 256 + (size_t)NCELL0 * 4, stream);
    hipMemsetAsync(feat0f, 0, (size_t)CAP0 * 128 * 4, stream);
    hipMemsetAsync(dout, 0, (size_t)out_size * 4, stream);

    // ---- constants ----
    k_prep<<<(PREP_TOT + 255)/256, 256, 0, stream>>>(w1, w2, w3, wd1, wd2,
        B1, B2, B3, Bd1, Bd2, bng, bnb, bnm, bnv, bnscale, bnshift);

    // ---- sparse structure ----
    k_count<<<(NV_ + 255)/256, 256, 0, stream>>>(coors, cntg);
    k_compact0<<<(NCELL0 + 255)/256, 256, 0, stream>>>(cntg, idx0, list0, counters + 0);
    k_scatter<<<(NV_*32 + 255)/256, 256, 0, stream>>>(vf, coors, cntg, idx0, feat0f);
    k_convert<<<(CAP0*16 + 255)/256, 256, 0, stream>>>(feat0f, feat0b, counters + 0);
    k_compact_dn<<<(NCELL1 + 255)/256, 256, 0, stream>>>(idx0, idx1, list1, counters + 1, NCELL1);
    k_compact_dn<<<(NCELL2 + 255)/256, 256, 0, stream>>>(idx1, idx2, list2, counters + 2, NCELL2);

    dim3 g27((CAP1 + 255)/256, 27, 2);
    k_nbr27<<<g27, 256, 0, stream>>>(list0, list1, idx0, idx1, nbr0T, nbr1T, counters);
    dim3 g3((CAP2 + 255)/256, 3, 2);
    k_nbr3<<<g3, 256, 0, stream>>>(list1, list2, idx0, idx1, dnb1T, dnb2T, counters);

    // ---- the five gather-GEMMs (M-tile 128, pipelined) ----
    k_gemm<27,false><<<(CAP0+127)/128, 256, 0, stream>>>(feat0b, nbr0T, CAP0, B1, feat1,
        counters + 0, bnscale + 0,   bnshift + 0,   nullptr, nullptr);
    k_gemm<3,false><<<(CAP1+127)/128, 256, 0, stream>>>(feat1, dnb1T, CAP1, Bd1, featd1,
        counters + 1, bnscale + 64,  bnshift + 64,  nullptr, nullptr);
    k_gemm<27,false><<<(CAP1+127)/128, 256, 0, stream>>>(featd1, nbr1T, CAP1, B2, feat2,
        counters + 1, bnscale + 128, bnshift + 128, nullptr, nullptr);
    k_gemm<27,false><<<(CAP1+127)/128, 256, 0, stream>>>(feat2, nbr1T, CAP1, B3, feat3,
        counters + 1, bnscale + 192, bnshift + 192, nullptr, nullptr);
    k_gemm<3,true><<<(CAP2+127)/128, 256, 0, stream>>>(feat3, dnb2T, CAP2, Bd2, nullptr,
        counters + 2, bnscale + 256, bnshift + 256, list2, dout);
}

// Round 9
// 369.103 us; speedup vs baseline: 2.2304x; 1.0378x over previous
//
#include <hip/hip_runtime.h>

typedef float floatx4 __attribute__((ext_vector_type(4)));
typedef __bf16 bf16x8 __attribute__((ext_vector_type(8)));

#define D0_ 19
#define H0_ 200
#define W0_ 176
#define HW_ (H0_*W0_)          // 35200
#define NCELL0 (D0_*HW_)       // 668800
#define D1_ 9
#define NCELL1 (D1_*HW_)       // 316800
#define D2_ 4
#define NCELL2 (D2_*HW_)       // 140800
#define NV_ 40000
#define CAP0 40000
#define CAP1 80000
#define CAP2 140800
#define EPS_ 1e-3f

__device__ __forceinline__ float bf2f(short s){
    union { unsigned u; float f; } x; x.u = ((unsigned)(unsigned short)s) << 16; return x.f;
}
__device__ __forceinline__ short f2bf(float f){
    union { float f; unsigned u; } x; x.f = f;
    unsigned r = x.u + 0x7fffu + ((x.u >> 16) & 1u);
    return (short)(r >> 16);
}

// ---------------- fused constant prep: BN consts + 5 weight repacks ----------------
__device__ __forceinline__ void repack_one(const float* w, short* Bout, int i, int KCsrc, int NSP){
    int k = i >> 6, n = i & 63;
    int ci = k & 127;
    int cis = (KCsrc == 128) ? ci : (ci & 63);
    short val = f2bf(w[(n * KCsrc + cis) * NSP + (k >> 7)]);
    int kc = k >> 5, lanehi = (k >> 3) & 3, jj = k & 7;
    int nt = n >> 4, lane = lanehi * 16 + (n & 15);
    Bout[((kc * 4 + nt) * 64 + lane) * 8 + jj] = val;
}

#define RP_BIG (3456*64)   // 221184
#define RP_SML (384*64)    // 24576

__global__ void k_prep(const float* w1, const float* w2, const float* w3,
                       const float* wd1, const float* wd2,
                       short* B1, short* B2, short* B3, short* Bd1, short* Bd2,
                       const float* g, const float* b, const float* m, const float* v,
                       float* scale, float* shift){
    int i = blockIdx.x * 256 + threadIdx.x;
    if (i < RP_BIG){ repack_one(w1, B1, i, 128, 27); return; }
    i -= RP_BIG;
    if (i < RP_BIG){ repack_one(w2, B2, i, 64, 27); return; }
    i -= RP_BIG;
    if (i < RP_BIG){ repack_one(w3, B3, i, 64, 27); return; }
    i -= RP_BIG;
    if (i < RP_SML){ repack_one(wd1, Bd1, i, 64, 3); return; }
    i -= RP_SML;
    if (i < RP_SML){ repack_one(wd2, Bd2, i, 64, 3); return; }
    i -= RP_SML;
    if (i < 5*64){
        float s = g[i] / sqrtf(v[i] + EPS_);
        scale[i] = s;
        shift[i] = b[i] - m[i] * s;
    }
}
#define PREP_TOT (3*RP_BIG + 2*RP_SML + 5*64)

// ---------------- voxel count per cell ----------------
__global__ void k_count(const int* coors, int* cntg){
    int v = blockIdx.x * 256 + threadIdx.x;
    if (v >= NV_) return;
    int z = coors[v*4+1], y = coors[v*4+2], x = coors[v*4+3];
    atomicAdd(&cntg[(z*H0_ + y)*W0_ + x], 1);
}

// ---------------- block-aggregated row assignment: ONE atomic per block ----------------
__device__ __forceinline__ int blk_rank(bool act, int* cnt, int& r_out){
    unsigned long long mask = __ballot(act);
    int lane = threadIdx.x & 63, wid = threadIdx.x >> 6;
    int wrank = __popcll(mask & ((1ull << lane) - 1));
    __shared__ int ws[4];
    __shared__ int blkbase;
    if (lane == 0) ws[wid] = __popcll(mask);
    __syncthreads();
    if (threadIdx.x == 0){
        int t0 = ws[0], t1 = ws[1], t2 = ws[2], t3 = ws[3];
        int tot = t0 + t1 + t2 + t3;
        blkbase = tot ? atomicAdd(cnt, tot) : 0;
        ws[0] = 0; ws[1] = t0; ws[2] = t0 + t1; ws[3] = t0 + t1 + t2;
    }
    __syncthreads();
    r_out = blkbase + ws[wid] + wrank;
    return 0;
}

// ---------------- compact level 0 ----------------
__global__ void k_compact0(const int* cntg, int* idx0, int* list0, int* cnt0){
    int c = blockIdx.x * 256 + threadIdx.x;
    bool act = (c < NCELL0) && (cntg[c] > 0);
    int r; blk_rank(act, cnt0, r);
    if (c >= NCELL0) return;
    if (act){
        idx0[c] = r;
        int z = c / HW_; int rem = c - z * HW_;
        int y = rem / W0_; int x = rem - y * W0_;
        list0[r] = (z << 16) | (y << 8) | x;
    } else idx0[c] = -1;
}

// ---------------- compact level 1/2 ----------------
__global__ void k_compact_dn(const int* idxsrc, int* idxdst, int* listdst, int* cnt,
                             int ncell){
    int c = blockIdx.x * 256 + threadIdx.x;
    bool act = false;
    int d = 0, y = 0, x = 0;
    if (c < ncell){
        d = c / HW_; int rem = c - d * HW_;
        y = rem / W0_; x = rem - y * W0_;
        #pragma unroll
        for (int j = 0; j < 3; ++j)
            act = act || (idxsrc[((2*d + j)*H0_ + y)*W0_ + x] >= 0);
    }
    int r; blk_rank(act, cnt, r);
    if (c >= ncell) return;
    if (act){
        idxdst[c] = r;
        listdst[r] = (d << 16) | (y << 8) | x;
    } else idxdst[c] = -1;
}

// ---------------- scatter fp32 features ----------------
__global__ void k_scatter(const float* vf, const int* coors, const int* cntg,
                          const int* idx0, float* feat0f){
    int u = blockIdx.x * 256 + threadIdx.x;
    if (u >= NV_ * 32) return;
    int v = u >> 5, c4 = u & 31;
    int z = coors[v*4+1], y = coors[v*4+2], x = coors[v*4+3];
    int cell = (z*H0_ + y)*W0_ + x;
    int row = idx0[cell];
    float4 s = ((const float4*)(vf + (long)v * 128))[c4];
    float* dst = feat0f + (long)row * 128 + c4 * 4;
    if (cntg[cell] == 1){
        *(float4*)dst = s;
    } else {
        atomicAdd(dst+0, s.x); atomicAdd(dst+1, s.y);
        atomicAdd(dst+2, s.z); atomicAdd(dst+3, s.w);
    }
}

// ---------------- fp32 -> bf16 convert ----------------
__global__ void k_convert(const float* f, short* b, const int* cntp){
    int n8 = cntp[0] * 16;
    int i = blockIdx.x * 256 + threadIdx.x;
    if (i >= n8) return;
    float4 a = ((const float4*)f)[i*2], c = ((const float4*)f)[i*2+1];
    short o[8] = { f2bf(a.x), f2bf(a.y), f2bf(a.z), f2bf(a.w),
                   f2bf(c.x), f2bf(c.y), f2bf(c.z), f2bf(c.w) };
    ((int4*)b)[i] = *(int4*)o;
}

// ---------------- transposed 27-tap neighbor tables: nbrT[j*cap + site] ----------------
__global__ void k_nbr27(const int* list0, const int* list1,
                        const int* idx0, const int* idx1,
                        int* nbr0T, int* nbr1T, const int* counters){
    int lvl = blockIdx.z;
    int j = blockIdx.y;
    int site = blockIdx.x * 256 + threadIdx.x;
    int M = counters[lvl];
    if (site >= M) return;
    const int* list = lvl ? list1 : list0;
    const int* idxg = lvl ? idx1 : idx0;
    int Dd = lvl ? D1_ : D0_;
    int cap = lvl ? CAP1 : CAP0;
    int cell = list[site];
    int z = cell >> 16, y = (cell >> 8) & 255, x = cell & 255;
    int nz = z + j/9 - 1, ny = y + (j/3)%3 - 1, nx = x + j%3 - 1;
    int r = -1;
    if ((unsigned)nz < (unsigned)Dd && (unsigned)ny < H0_ && (unsigned)nx < W0_)
        r = idxg[(nz*H0_ + ny)*W0_ + nx];
    (lvl ? nbr1T : nbr0T)[j * cap + site] = r;
}

// ---------------- transposed 3-tap downsample tables ----------------
__global__ void k_nbr3(const int* list1, const int* list2,
                       const int* idx0, const int* idx1,
                       int* dnb1T, int* dnb2T, const int* counters){
    int lvl = blockIdx.z;                // 0: dn1, 1: dn2
    int j = blockIdx.y;
    int site = blockIdx.x * 256 + threadIdx.x;
    int M = counters[lvl + 1];
    if (site >= M) return;
    const int* list = lvl ? list2 : list1;
    const int* idxg = lvl ? idx1 : idx0;
    int cap = lvl ? CAP2 : CAP1;
    int cell = list[site];
    int d = cell >> 16, y = (cell >> 8) & 255, x = cell & 255;
    (lvl ? dnb2T : dnb1T)[j * cap + site] = idxg[((2*d + j)*H0_ + y)*W0_ + x];
}

// ---------------- gather-GEMM: chunk-granular rotating-buffer pipeline ----------------
// M-tile 128/block; wave owns row-groups wave and wave+4. Chunks g = tap*4 + kc.
// B chunk prefetched 2 chunks ahead (3 rotating bufs); A for tap t+1 loaded
// 2-per-chunk during tap t (double buffer); nbr 2 taps ahead. The MFMA section
// consumes only registers loaded >=2 chunks earlier -> no dependent loads.
template<int NNBR, bool FINAL>
__global__ __launch_bounds__(256) void k_gemm(
    const short* __restrict__ featA, const int* __restrict__ nbrT, int nstride,
    const short* __restrict__ Bs, short* __restrict__ out,
    const int* __restrict__ cntp,
    const float* __restrict__ scale, const float* __restrict__ shift,
    const int* __restrict__ list, float* __restrict__ dout)
{
    int M = *cntp;
    int m0 = blockIdx.x * 128;
    if (m0 >= M) return;
    int tid = threadIdx.x;
    int wave = tid >> 6, lane = tid & 63;
    int m16 = lane & 15;
    int koff = (lane >> 4) * 8;

    int row0 = m0 + wave * 16 + m16;
    int row1 = row0 + 64;
    bool ok0 = row0 < M, ok1 = row1 < M;
    const short* Bl = Bs + (long)lane * 8;

    floatx4 acc0[4] = {}, acc1[4] = {};
    bf16x8 Bpf[3][4];
    bf16x8 A0[2][4], A1[2][4];
    const bf16x8 z8 = {0,0,0,0,0,0,0,0};

    auto loadB = [&](int buf, int g){
        #pragma unroll
        for (int nt = 0; nt < 4; ++nt)
            Bpf[buf][nt] = *(const bf16x8*)(Bl + (long)(g*4 + nt) * 512);
    };
    auto loadA1 = [&](bf16x8* dst, int r, int kc){
        dst[kc] = (r >= 0) ? *(const bf16x8*)(featA + (long)r*128 + koff + kc*32) : z8;
    };

    // prologue: tap0 A (8 loads), nbr tap1, B chunks 0 & 1
    int rc0 = ok0 ? nbrT[row0] : -1;
    int rc1 = ok1 ? nbrT[row1] : -1;
    #pragma unroll
    for (int kc = 0; kc < 4; ++kc){ loadA1(A0[0], rc0, kc); loadA1(A1[0], rc1, kc); }
    int rb0 = (NNBR > 1 && ok0) ? nbrT[nstride + row0] : -1;
    int rb1 = (NNBR > 1 && ok1) ? nbrT[nstride + row1] : -1;
    loadB(0, 0);
    loadB(1, 1);
    int ra0 = -1, ra1 = -1;

    #pragma unroll
    for (int g = 0; g < NNBR*4; ++g){
        const int t = g >> 2, kc = g & 3, buf = g % 3;
        if (g + 2 < NNBR*4) loadB((g + 2) % 3, g + 2);
        if (t + 1 < NNBR){ loadA1(A0[(t+1)&1], rb0, kc); loadA1(A1[(t+1)&1], rb1, kc); }
        if (kc == 0 && t + 2 < NNBR){
            ra0 = ok0 ? nbrT[(t+2)*nstride + row0] : -1;
            ra1 = ok1 ? nbrT[(t+2)*nstride + row1] : -1;
        }
        bf16x8 a0 = A0[t&1][kc], a1 = A1[t&1][kc];
        #pragma unroll
        for (int nt = 0; nt < 4; ++nt)
            acc0[nt] = __builtin_amdgcn_mfma_f32_16x16x32_bf16(a0, Bpf[buf][nt], acc0[nt], 0, 0, 0);
        #pragma unroll
        for (int nt = 0; nt < 4; ++nt)
            acc1[nt] = __builtin_amdgcn_mfma_f32_16x16x32_bf16(a1, Bpf[buf][nt], acc1[nt], 0, 0, 0);
        if (kc == 3){ rb0 = ra0; rb1 = ra1; }
    }

    // epilogue: C/D layout col = lane&15, row = (lane>>4)*4 + reg
    int n16 = lane & 15;
    #pragma unroll
    for (int rg = 0; rg < 2; ++rg){
        const floatx4* ac = rg ? acc1 : acc0;
        int mb = m0 + (wave + rg*4) * 16 + (lane >> 4) * 4;
        #pragma unroll
        for (int nt = 0; nt < 4; ++nt){
            int n = nt * 16 + n16;
            float sc = scale[n], sh = shift[n];
            #pragma unroll
            for (int r = 0; r < 4; ++r){
                int site = mb + r;
                if (site < M){
                    float y = fmaxf(ac[nt][r] * sc + sh, 0.f);
                    if (FINAL){
                        int cell = list[site];
                        int d = cell >> 16, yy = (cell >> 8) & 255, xx = cell & 255;
                        dout[((n*4 + d)*H0_ + yy)*W0_ + xx] = y;
                    } else {
                        short hi = f2bf(y);
                        float lo = y - bf2f(hi);
                        out[(long)site*128 + n]      = hi;
                        out[(long)site*128 + 64 + n] = f2bf(lo);
                    }
                }
            }
        }
    }
}

extern "C" void kernel_launch(void* const* d_in, const int* in_sizes, int n_in,
                              void* d_out, int out_size, void* d_ws, size_t ws_size,
                              hipStream_t stream){
    const float* vf   = (const float*)d_in[0];
    const int*   coors= (const int*)  d_in[1];
    const float* w1   = (const float*)d_in[3];
    const float* wd1  = (const float*)d_in[4];
    const float* w2   = (const float*)d_in[5];
    const float* w3   = (const float*)d_in[6];
    const float* wd2  = (const float*)d_in[7];
    const float* bng  = (const float*)d_in[8];
    const float* bnb  = (const float*)d_in[9];
    const float* bnm  = (const float*)d_in[10];
    const float* bnv  = (const float*)d_in[11];
    float* dout = (float*)d_out;

    char* ws = (char*)d_ws;
    size_t off = 0;
    auto alloc = [&](size_t bytes)->char* {
        char* p = ws + off;
        off += (bytes + 255) & ~(size_t)255;
        return p;
    };

    int*   counters = (int*)  alloc(256);                    // [0]=cnt0 [1]=cnt1 [2]=cnt2
    int*   cntg     = (int*)  alloc((size_t)NCELL0 * 4);
    int*   idx0     = (int*)  alloc((size_t)NCELL0 * 4);
    int*   idx1     = (int*)  alloc((size_t)NCELL1 * 4);
    int*   idx2     = (int*)  alloc((size_t)NCELL2 * 4);
    int*   list0    = (int*)  alloc((size_t)CAP0 * 4);
    int*   list1    = (int*)  alloc((size_t)CAP1 * 4);
    int*   list2    = (int*)  alloc((size_t)CAP2 * 4);
    float* feat0f   = (float*)alloc((size_t)CAP0 * 128 * 4);
    short* feat0b   = (short*)alloc((size_t)CAP0 * 128 * 2);
    short* feat1    = (short*)alloc((size_t)CAP0 * 128 * 2);
    short* featd1   = (short*)alloc((size_t)CAP1 * 128 * 2);
    short* feat3    = (short*)alloc((size_t)CAP1 * 128 * 2);
    int*   nbr0T    = (int*)  alloc((size_t)CAP0 * 27 * 4);
    int*   nbr1T    = (int*)  alloc((size_t)CAP1 * 27 * 4);
    int*   dnb1T    = (int*)  alloc((size_t)CAP1 * 3 * 4);
    int*   dnb2T    = (int*)  alloc((size_t)CAP2 * 3 * 4);
    short* B1  = (short*)alloc((size_t)3456 * 64 * 2);
    short* B2  = (short*)alloc((size_t)3456 * 64 * 2);
    short* B3  = (short*)alloc((size_t)3456 * 64 * 2);
    short* Bd1 = (short*)alloc((size_t)384 * 64 * 2);
    short* Bd2 = (short*)alloc((size_t)384 * 64 * 2);
    float* bnscale = (float*)alloc(5 * 64 * 4);
    float* bnshift = (float*)alloc(5 * 64 * 4);
    short* feat2 = (short*)feat0f;   // alias: feat0f dead after k_convert

    // ---- zero (ws/d_out poisoned 0xAA) ----
    hipMemsetAsync(counters, 0, 256 + (size_t)NCELL0 * 4, stream);
    hipMemsetAsync(feat0f, 0, (size_t)CAP0 * 128 * 4, stream);
    hipMemsetAsync(dout, 0, (size_t)out_size * 4, stream);

    // ---- constants ----
    k_prep<<<(PREP_TOT + 255)/256, 256, 0, stream>>>(w1, w2, w3, wd1, wd2,
        B1, B2, B3, Bd1, Bd2, bng, bnb, bnm, bnv, bnscale, bnshift);

    // ---- sparse structure ----
    k_count<<<(NV_ + 255)/256, 256, 0, stream>>>(coors, cntg);
    k_compact0<<<(NCELL0 + 255)/256, 256, 0, stream>>>(cntg, idx0, list0, counters + 0);
    k_scatter<<<(NV_*32 + 255)/256, 256, 0, stream>>>(vf, coors, cntg, idx0, feat0f);
    k_convert<<<(CAP0*16 + 255)/256, 256, 0, stream>>>(feat0f, feat0b, counters + 0);
    k_compact_dn<<<(NCELL1 + 255)/256, 256, 0, stream>>>(idx0, idx1, list1, counters + 1, NCELL1);
    k_compact_dn<<<(NCELL2 + 255)/256, 256, 0, stream>>>(idx1, idx2, list2, counters + 2, NCELL2);

    dim3 g27((CAP1 + 255)/256, 27, 2);
    k_nbr27<<<g27, 256, 0, stream>>>(list0, list1, idx0, idx1, nbr0T, nbr1T, counters);
    dim3 g3((CAP2 + 255)/256, 3, 2);
    k_nbr3<<<g3, 256, 0, stream>>>(list1, list2, idx0, idx1, dnb1T, dnb2T, counters);

    // ---- the five gather-GEMMs (M-tile 128, chunk-pipelined) ----
    k_gemm<27,false><<<(CAP0+127)/128, 256, 0, stream>>>(feat0b, nbr0T, CAP0, B1, feat1,
        counters + 0, bnscale + 0,   bnshift + 0,   nullptr, nullptr);
    k_gemm<3,false><<<(CAP1+127)/128, 256, 0, stream>>>(feat1, dnb1T, CAP1, Bd1, featd1,
        counters + 1, bnscale + 64,  bnshift + 64,  nullptr, nullptr);
    k_gemm<27,false><<<(CAP1+127)/128, 256, 0, stream>>>(featd1, nbr1T, CAP1, B2, feat2,
        counters + 1, bnscale + 128, bnshift + 128, nullptr, nullptr);
    k_gemm<27,false><<<(CAP1+127)/128, 256, 0, stream>>>(feat2, nbr1T, CAP1, B3, feat3,
        counters + 1, bnscale + 192, bnshift + 192, nullptr, nullptr);
    k_gemm<3,true><<<(CAP2+127)/128, 256, 0, stream>>>(feat3, dnb2T, CAP2, Bd2, nullptr,
        counters + 2, bnscale + 256, bnshift + 256, list2, dout);
}

// Round 10
// 354.806 us; speedup vs baseline: 2.3203x; 1.0403x over previous
//
#include <hip/hip_runtime.h>

typedef float floatx4 __attribute__((ext_vector_type(4)));
typedef __bf16 bf16x8 __attribute__((ext_vector_type(8)));

#define D0_ 19
#define H0_ 200
#define W0_ 176
#define HW_ (H0_*W0_)          // 35200
#define NCELL0 (D0_*HW_)       // 668800
#define D1_ 9
#define NCELL1 (D1_*HW_)       // 316800
#define D2_ 4
#define NCELL2 (D2_*HW_)       // 140800
#define NV_ 40000
#define CAP0 40000
#define CAP1 80000
#define CAP2 140800
#define EPS_ 1e-3f

typedef __attribute__((address_space(1))) const unsigned int* gas_t;
typedef __attribute__((address_space(3))) unsigned int* las_t;

__device__ __forceinline__ float bf2f(short s){
    union { unsigned u; float f; } x; x.u = ((unsigned)(unsigned short)s) << 16; return x.f;
}
__device__ __forceinline__ short f2bf(float f){
    union { float f; unsigned u; } x; x.f = f;
    unsigned r = x.u + 0x7fffu + ((x.u >> 16) & 1u);
    return (short)(r >> 16);
}

// ---------------- fused constant prep: BN consts + 5 weight repacks ----------------
__device__ __forceinline__ void repack_one(const float* w, short* Bout, int i, int KCsrc, int NSP){
    int k = i >> 6, n = i & 63;
    int ci = k & 127;
    int cis = (KCsrc == 128) ? ci : (ci & 63);
    short val = f2bf(w[(n * KCsrc + cis) * NSP + (k >> 7)]);
    int kc = k >> 5, lanehi = (k >> 3) & 3, jj = k & 7;
    int nt = n >> 4, lane = lanehi * 16 + (n & 15);
    Bout[((kc * 4 + nt) * 64 + lane) * 8 + jj] = val;
}

#define RP_BIG (3456*64)   // 221184
#define RP_SML (384*64)    // 24576

__global__ void k_prep(const float* w1, const float* w2, const float* w3,
                       const float* wd1, const float* wd2,
                       short* B1, short* B2, short* B3, short* Bd1, short* Bd2,
                       const float* g, const float* b, const float* m, const float* v,
                       float* scale, float* shift){
    int i = blockIdx.x * 256 + threadIdx.x;
    if (i < RP_BIG){ repack_one(w1, B1, i, 128, 27); return; }
    i -= RP_BIG;
    if (i < RP_BIG){ repack_one(w2, B2, i, 64, 27); return; }
    i -= RP_BIG;
    if (i < RP_BIG){ repack_one(w3, B3, i, 64, 27); return; }
    i -= RP_BIG;
    if (i < RP_SML){ repack_one(wd1, Bd1, i, 64, 3); return; }
    i -= RP_SML;
    if (i < RP_SML){ repack_one(wd2, Bd2, i, 64, 3); return; }
    i -= RP_SML;
    if (i < 5*64){
        float s = g[i] / sqrtf(v[i] + EPS_);
        scale[i] = s;
        shift[i] = b[i] - m[i] * s;
    }
}
#define PREP_TOT (3*RP_BIG + 2*RP_SML + 5*64)

// ---------------- voxel count per cell ----------------
__global__ void k_count(const int* coors, int* cntg){
    int v = blockIdx.x * 256 + threadIdx.x;
    if (v >= NV_) return;
    int z = coors[v*4+1], y = coors[v*4+2], x = coors[v*4+3];
    atomicAdd(&cntg[(z*H0_ + y)*W0_ + x], 1);
}

// ---------------- block-aggregated row assignment: ONE atomic per block ----------------
__device__ __forceinline__ int blk_rank(bool act, int* cnt, int& r_out){
    unsigned long long mask = __ballot(act);
    int lane = threadIdx.x & 63, wid = threadIdx.x >> 6;
    int wrank = __popcll(mask & ((1ull << lane) - 1));
    __shared__ int ws[4];
    __shared__ int blkbase;
    if (lane == 0) ws[wid] = __popcll(mask);
    __syncthreads();
    if (threadIdx.x == 0){
        int t0 = ws[0], t1 = ws[1], t2 = ws[2], t3 = ws[3];
        int tot = t0 + t1 + t2 + t3;
        blkbase = tot ? atomicAdd(cnt, tot) : 0;
        ws[0] = 0; ws[1] = t0; ws[2] = t0 + t1; ws[3] = t0 + t1 + t2;
    }
    __syncthreads();
    r_out = blkbase + ws[wid] + wrank;
    return 0;
}

// ---------------- compact level 0 ----------------
__global__ void k_compact0(const int* cntg, int* idx0, int* list0, int* cnt0){
    int c = blockIdx.x * 256 + threadIdx.x;
    bool act = (c < NCELL0) && (cntg[c] > 0);
    int r; blk_rank(act, cnt0, r);
    if (c >= NCELL0) return;
    if (act){
        idx0[c] = r;
        int z = c / HW_; int rem = c - z * HW_;
        int y = rem / W0_; int x = rem - y * W0_;
        list0[r] = (z << 16) | (y << 8) | x;
    } else idx0[c] = -1;
}

// ---------------- compact level 1/2 ----------------
__global__ void k_compact_dn(const int* idxsrc, int* idxdst, int* listdst, int* cnt,
                             int ncell){
    int c = blockIdx.x * 256 + threadIdx.x;
    bool act = false;
    int d = 0, y = 0, x = 0;
    if (c < ncell){
        d = c / HW_; int rem = c - d * HW_;
        y = rem / W0_; x = rem - y * W0_;
        #pragma unroll
        for (int j = 0; j < 3; ++j)
            act = act || (idxsrc[((2*d + j)*H0_ + y)*W0_ + x] >= 0);
    }
    int r; blk_rank(act, cnt, r);
    if (c >= ncell) return;
    if (act){
        idxdst[c] = r;
        listdst[r] = (d << 16) | (y << 8) | x;
    } else idxdst[c] = -1;
}

// ---------------- scatter fp32 features ----------------
__global__ void k_scatter(const float* vf, const int* coors, const int* cntg,
                          const int* idx0, float* feat0f){
    int u = blockIdx.x * 256 + threadIdx.x;
    if (u >= NV_ * 32) return;
    int v = u >> 5, c4 = u & 31;
    int z = coors[v*4+1], y = coors[v*4+2], x = coors[v*4+3];
    int cell = (z*H0_ + y)*W0_ + x;
    int row = idx0[cell];
    float4 s = ((const float4*)(vf + (long)v * 128))[c4];
    float* dst = feat0f + (long)row * 128 + c4 * 4;
    if (cntg[cell] == 1){
        *(float4*)dst = s;
    } else {
        atomicAdd(dst+0, s.x); atomicAdd(dst+1, s.y);
        atomicAdd(dst+2, s.z); atomicAdd(dst+3, s.w);
    }
}

// ---------------- fp32 -> bf16 convert ----------------
__global__ void k_convert(const float* f, short* b, const int* cntp){
    int n8 = cntp[0] * 16;
    int i = blockIdx.x * 256 + threadIdx.x;
    if (i >= n8) return;
    float4 a = ((const float4*)f)[i*2], c = ((const float4*)f)[i*2+1];
    short o[8] = { f2bf(a.x), f2bf(a.y), f2bf(a.z), f2bf(a.w),
                   f2bf(c.x), f2bf(c.y), f2bf(c.z), f2bf(c.w) };
    ((int4*)b)[i] = *(int4*)o;
}

// ---------------- transposed 27-tap neighbor tables: nbrT[j*cap + site] ----------------
__global__ void k_nbr27(const int* list0, const int* list1,
                        const int* idx0, const int* idx1,
                        int* nbr0T, int* nbr1T, const int* counters){
    int lvl = blockIdx.z;
    int j = blockIdx.y;
    int site = blockIdx.x * 256 + threadIdx.x;
    int M = counters[lvl];
    if (site >= M) return;
    const int* list = lvl ? list1 : list0;
    const int* idxg = lvl ? idx1 : idx0;
    int Dd = lvl ? D1_ : D0_;
    int cap = lvl ? CAP1 : CAP0;
    int cell = list[site];
    int z = cell >> 16, y = (cell >> 8) & 255, x = cell & 255;
    int nz = z + j/9 - 1, ny = y + (j/3)%3 - 1, nx = x + j%3 - 1;
    int r = -1;
    if ((unsigned)nz < (unsigned)Dd && (unsigned)ny < H0_ && (unsigned)nx < W0_)
        r = idxg[(nz*H0_ + ny)*W0_ + nx];
    (lvl ? nbr1T : nbr0T)[j * cap + site] = r;
}

// ---------------- transposed 3-tap downsample tables ----------------
__global__ void k_nbr3(const int* list1, const int* list2,
                       const int* idx0, const int* idx1,
                       int* dnb1T, int* dnb2T, const int* counters){
    int lvl = blockIdx.z;                // 0: dn1, 1: dn2
    int j = blockIdx.y;
    int site = blockIdx.x * 256 + threadIdx.x;
    int M = counters[lvl + 1];
    if (site >= M) return;
    const int* list = lvl ? list2 : list1;
    const int* idxg = lvl ? idx1 : idx0;
    int cap = lvl ? CAP2 : CAP1;
    int cell = list[site];
    int d = cell >> 16, y = (cell >> 8) & 255, x = cell & 255;
    (lvl ? dnb2T : dnb1T)[j * cap + site] = idxg[((2*d + j)*H0_ + y)*W0_ + x];
}

// ---------------- gather-GEMM: B staged in LDS per block (kills 4x B L2 traffic) ----------------
// M-tile 128/block; wave owns row-groups wave and wave+4. Per tap: B(t+1) staged
// by async global_load_lds (double buffer, 1 barrier/tap); A(t+1) register-
// prefetched; fragments read via conflict-free contiguous ds_read_b128.
template<int NNBR, bool FINAL>
__global__ __launch_bounds__(256) void k_gemm(
    const short* __restrict__ featA, const int* __restrict__ nbrT, int nstride,
    const short* __restrict__ Bs, short* __restrict__ out,
    const int* __restrict__ cntp,
    const float* __restrict__ scale, const float* __restrict__ shift,
    const int* __restrict__ list, float* __restrict__ dout)
{
    __shared__ short Blds[2][16*64*8];   // 2 x 16 KB (frag-major, lane*16B inside frag)
    int M = *cntp;
    int m0 = blockIdx.x * 128;
    if (m0 >= M) return;
    int tid = threadIdx.x;
    int wave = tid >> 6, lane = tid & 63;
    int m16 = lane & 15;
    int koff = (lane >> 4) * 8;

    int row0 = m0 + wave * 16 + m16;
    int row1 = row0 + 64;
    bool ok0 = row0 < M, ok1 = row1 < M;

    floatx4 acc0[4] = {}, acc1[4] = {};
    bf16x8 A0[2][4], A1[2][4];
    const bf16x8 z8 = {0,0,0,0,0,0,0,0};

    // wave w stages frags w*4..w*4+3 of tap j into buffer b
    auto stageB = [&](int j, int b){
        #pragma unroll
        for (int f = 0; f < 4; ++f){
            int frag = wave * 4 + f;
            const short* g = Bs + (((long)j * 16 + frag) * 64 + lane) * 8;
            __builtin_amdgcn_global_load_lds((gas_t)g, (las_t)&Blds[b][frag * 512],
                                             16, 0, 0);
        }
    };
    auto loadA1 = [&](bf16x8* dst, int r, int kc){
        dst[kc] = (r >= 0) ? *(const bf16x8*)(featA + (long)r*128 + koff + kc*32) : z8;
    };

    // prologue: stage B(0), load A(0), nbr(1)
    int rc0 = ok0 ? nbrT[row0] : -1;
    int rc1 = ok1 ? nbrT[row1] : -1;
    stageB(0, 0);
    #pragma unroll
    for (int kc = 0; kc < 4; ++kc){ loadA1(A0[0], rc0, kc); loadA1(A1[0], rc1, kc); }
    int rb0 = (NNBR > 1 && ok0) ? nbrT[nstride + row0] : -1;
    int rb1 = (NNBR > 1 && ok1) ? nbrT[nstride + row1] : -1;
    int ra0 = -1, ra1 = -1;
    __syncthreads();

    #pragma unroll
    for (int t = 0; t < NNBR; ++t){
        if (t + 1 < NNBR){
            stageB(t + 1, (t + 1) & 1);                       // async -> LDS
            #pragma unroll
            for (int kc = 0; kc < 4; ++kc){ loadA1(A0[(t+1)&1], rb0, kc); loadA1(A1[(t+1)&1], rb1, kc); }
        }
        if (t + 2 < NNBR){
            ra0 = ok0 ? nbrT[(t+2)*nstride + row0] : -1;
            ra1 = ok1 ? nbrT[(t+2)*nstride + row1] : -1;
        }
        const short* Bb = Blds[t & 1];
        #pragma unroll
        for (int kc = 0; kc < 4; ++kc){
            bf16x8 b[4];
            #pragma unroll
            for (int nt = 0; nt < 4; ++nt)
                b[nt] = *(const bf16x8*)&Bb[((kc*4 + nt) * 64 + lane) * 8];
            bf16x8 a0 = A0[t&1][kc], a1 = A1[t&1][kc];
            #pragma unroll
            for (int nt = 0; nt < 4; ++nt)
                acc0[nt] = __builtin_amdgcn_mfma_f32_16x16x32_bf16(a0, b[nt], acc0[nt], 0, 0, 0);
            #pragma unroll
            for (int nt = 0; nt < 4; ++nt)
                acc1[nt] = __builtin_amdgcn_mfma_f32_16x16x32_bf16(a1, b[nt], acc1[nt], 0, 0, 0);
        }
        rb0 = ra0; rb1 = ra1;
        __syncthreads();                                      // drains DMA + guards dbuf
    }

    // epilogue: C/D layout col = lane&15, row = (lane>>4)*4 + reg
    int n16 = lane & 15;
    #pragma unroll
    for (int rg = 0; rg < 2; ++rg){
        const floatx4* ac = rg ? acc1 : acc0;
        int mb = m0 + (wave + rg*4) * 16 + (lane >> 4) * 4;
        #pragma unroll
        for (int nt = 0; nt < 4; ++nt){
            int n = nt * 16 + n16;
            float sc = scale[n], sh = shift[n];
            #pragma unroll
            for (int r = 0; r < 4; ++r){
                int site = mb + r;
                if (site < M){
                    float y = fmaxf(ac[nt][r] * sc + sh, 0.f);
                    if (FINAL){
                        int cell = list[site];
                        int d = cell >> 16, yy = (cell >> 8) & 255, xx = cell & 255;
                        dout[((n*4 + d)*H0_ + yy)*W0_ + xx] = y;
                    } else {
                        short hi = f2bf(y);
                        float lo = y - bf2f(hi);
                        out[(long)site*128 + n]      = hi;
                        out[(long)site*128 + 64 + n] = f2bf(lo);
                    }
                }
            }
        }
    }
}

extern "C" void kernel_launch(void* const* d_in, const int* in_sizes, int n_in,
                              void* d_out, int out_size, void* d_ws, size_t ws_size,
                              hipStream_t stream){
    const float* vf   = (const float*)d_in[0];
    const int*   coors= (const int*)  d_in[1];
    const float* w1   = (const float*)d_in[3];
    const float* wd1  = (const float*)d_in[4];
    const float* w2   = (const float*)d_in[5];
    const float* w3   = (const float*)d_in[6];
    const float* wd2  = (const float*)d_in[7];
    const float* bng  = (const float*)d_in[8];
    const float* bnb  = (const float*)d_in[9];
    const float* bnm  = (const float*)d_in[10];
    const float* bnv  = (const float*)d_in[11];
    float* dout = (float*)d_out;

    char* ws = (char*)d_ws;
    size_t off = 0;
    auto alloc = [&](size_t bytes)->char* {
        char* p = ws + off;
        off += (bytes + 255) & ~(size_t)255;
        return p;
    };

    int*   counters = (int*)  alloc(256);                    // [0]=cnt0 [1]=cnt1 [2]=cnt2
    int*   cntg     = (int*)  alloc((size_t)NCELL0 * 4);
    int*   idx0     = (int*)  alloc((size_t)NCELL0 * 4);
    int*   idx1     = (int*)  alloc((size_t)NCELL1 * 4);
    int*   idx2     = (int*)  alloc((size_t)NCELL2 * 4);
    int*   list0    = (int*)  alloc((size_t)CAP0 * 4);
    int*   list1    = (int*)  alloc((size_t)CAP1 * 4);
    int*   list2    = (int*)  alloc((size_t)CAP2 * 4);
    float* feat0f   = (float*)alloc((size_t)CAP0 * 128 * 4);
    short* feat0b   = (short*)alloc((size_t)CAP0 * 128 * 2);
    short* feat1    = (short*)alloc((size_t)CAP0 * 128 * 2);
    short* featd1   = (short*)alloc((size_t)CAP1 * 128 * 2);
    short* feat3    = (short*)alloc((size_t)CAP1 * 128 * 2);
    int*   nbr0T    = (int*)  alloc((size_t)CAP0 * 27 * 4);
    int*   nbr1T    = (int*)  alloc((size_t)CAP1 * 27 * 4);
    int*   dnb1T    = (int*)  alloc((size_t)CAP1 * 3 * 4);
    int*   dnb2T    = (int*)  alloc((size_t)CAP2 * 3 * 4);
    short* B1  = (short*)alloc((size_t)3456 * 64 * 2);
    short* B2  = (short*)alloc((size_t)3456 * 64 * 2);
    short* B3  = (short*)alloc((size_t)3456 * 64 * 2);
    short* Bd1 = (short*)alloc((size_t)384 * 64 * 2);
    short* Bd2 = (short*)alloc((size_t)384 * 64 * 2);
    float* bnscale = (float*)alloc(5 * 64 * 4);
    float* bnshift = (float*)alloc(5 * 64 * 4);
    short* feat2 = (short*)feat0f;   // alias: feat0f dead after k_convert

    // ---- zero (ws/d_out poisoned 0xAA) ----
    hipMemsetAsync(counters, 0, 256 + (size_t)NCELL0 * 4, stream);
    hipMemsetAsync(feat0f, 0, (size_t)CAP0 * 128 * 4, stream);
    hipMemsetAsync(dout, 0, (size_t)out_size * 4, stream);

    // ---- constants ----
    k_prep<<<(PREP_TOT + 255)/256, 256, 0, stream>>>(w1, w2, w3, wd1, wd2,
        B1, B2, B3, Bd1, Bd2, bng, bnb, bnm, bnv, bnscale, bnshift);

    // ---- sparse structure ----
    k_count<<<(NV_ + 255)/256, 256, 0, stream>>>(coors, cntg);
    k_compact0<<<(NCELL0 + 255)/256, 256, 0, stream>>>(cntg, idx0, list0, counters + 0);
    k_scatter<<<(NV_*32 + 255)/256, 256, 0, stream>>>(vf, coors, cntg, idx0, feat0f);
    k_convert<<<(CAP0*16 + 255)/256, 256, 0, stream>>>(feat0f, feat0b, counters + 0);
    k_compact_dn<<<(NCELL1 + 255)/256, 256, 0, stream>>>(idx0, idx1, list1, counters + 1, NCELL1);
    k_compact_dn<<<(NCELL2 + 255)/256, 256, 0, stream>>>(idx1, idx2, list2, counters + 2, NCELL2);

    dim3 g27((CAP1 + 255)/256, 27, 2);
    k_nbr27<<<g27, 256, 0, stream>>>(list0, list1, idx0, idx1, nbr0T, nbr1T, counters);
    dim3 g3((CAP2 + 255)/256, 3, 2);
    k_nbr3<<<g3, 256, 0, stream>>>(list1, list2, idx0, idx1, dnb1T, dnb2T, counters);

    // ---- the five gather-GEMMs (M-tile 128, LDS-staged B) ----
    k_gemm<27,false><<<(CAP0+127)/128, 256, 0, stream>>>(feat0b, nbr0T, CAP0, B1, feat1,
        counters + 0, bnscale + 0,   bnshift + 0,   nullptr, nullptr);
    k_gemm<3,false><<<(CAP1+127)/128, 256, 0, stream>>>(feat1, dnb1T, CAP1, Bd1, featd1,
        counters + 1, bnscale + 64,  bnshift + 64,  nullptr, nullptr);
    k_gemm<27,false><<<(CAP1+127)/128, 256, 0, stream>>>(featd1, nbr1T, CAP1, B2, feat2,
        counters + 1, bnscale + 128, bnshift + 128, nullptr, nullptr);
    k_gemm<27,false><<<(CAP1+127)/128, 256, 0, stream>>>(feat2, nbr1T, CAP1, B3, feat3,
        counters + 1, bnscale + 192, bnshift + 192, nullptr, nullptr);
    k_gemm<3,true><<<(CAP2+127)/128, 256, 0, stream>>>(feat3, dnb2T, CAP2, Bd2, nullptr,
        counters + 2, bnscale + 256, bnshift + 256, list2, dout);
}

// Round 11
// 322.105 us; speedup vs baseline: 2.5558x; 1.1015x over previous
//
#include <hip/hip_runtime.h>

typedef float floatx4 __attribute__((ext_vector_type(4)));
typedef _Float16 f16x8 __attribute__((ext_vector_type(8)));

#define D0_ 19
#define H0_ 200
#define W0_ 176
#define HW_ (H0_*W0_)          // 35200
#define NCELL0 (D0_*HW_)       // 668800
#define D1_ 9
#define NCELL1 (D1_*HW_)       // 316800
#define D2_ 4
#define NCELL2 (D2_*HW_)       // 140800
#define NV_ 40000
#define CAP0 40000
#define CAP1 80000
#define CAP2 140800
#define EPS_ 1e-3f

typedef __attribute__((address_space(1))) const unsigned int* gas_t;
typedef __attribute__((address_space(3))) unsigned int* las_t;

__device__ __forceinline__ short f2h(float f){
    _Float16 h = (_Float16)f;
    short s; __builtin_memcpy(&s, &h, 2); return s;
}

// ---------------- fused constant prep: BN consts + 5 weight repacks (fp16, no dup) ----------------
// K-index: k = j*KCsrc + ci. dest frag = k>>5 chunks; within: lane=((k>>3)&3)*16+(n&15), jj=k&7.
// Bout[((chunk*4 + nt)*64 + lane)*8 + jj]
__device__ __forceinline__ void repack_one(const float* w, short* Bout, int i,
                                           int KCsrc, int kshift, int NSP){
    int k = i >> 6, n = i & 63;
    int j = k >> kshift;
    int ci = k & (KCsrc - 1);
    short val = f2h(w[(n * KCsrc + ci) * NSP + j]);   // exact: weights bf16-rounded
    int chunk = k >> 5, lanehi = (k >> 3) & 3, jj = k & 7;
    int nt = n >> 4, lane = lanehi * 16 + (n & 15);
    Bout[((chunk * 4 + nt) * 64 + lane) * 8 + jj] = val;
}

#define RP1 (3456*64)   // 221184
#define RP2 (1728*64)   // 110592
#define RPD (192*64)    // 12288

__global__ void k_prep(const float* w1, const float* w2, const float* w3,
                       const float* wd1, const float* wd2,
                       short* B1, short* B2, short* B3, short* Bd1, short* Bd2,
                       const float* g, const float* b, const float* m, const float* v,
                       float* scale, float* shift){
    int i = blockIdx.x * 256 + threadIdx.x;
    if (i < RP1){ repack_one(w1, B1, i, 128, 7, 27); return; }
    i -= RP1;
    if (i < RP2){ repack_one(w2, B2, i, 64, 6, 27); return; }
    i -= RP2;
    if (i < RP2){ repack_one(w3, B3, i, 64, 6, 27); return; }
    i -= RP2;
    if (i < RPD){ repack_one(wd1, Bd1, i, 64, 6, 3); return; }
    i -= RPD;
    if (i < RPD){ repack_one(wd2, Bd2, i, 64, 6, 3); return; }
    i -= RPD;
    if (i < 5*64){
        float s = g[i] / sqrtf(v[i] + EPS_);
        scale[i] = s;
        shift[i] = b[i] - m[i] * s;
    }
}
#define PREP_TOT (RP1 + 2*RP2 + 2*RPD + 5*64)

// ---------------- voxel count per cell ----------------
__global__ void k_count(const int* coors, int* cntg){
    int v = blockIdx.x * 256 + threadIdx.x;
    if (v >= NV_) return;
    int z = coors[v*4+1], y = coors[v*4+2], x = coors[v*4+3];
    atomicAdd(&cntg[(z*H0_ + y)*W0_ + x], 1);
}

// ---------------- block-aggregated row assignment: ONE atomic per block ----------------
__device__ __forceinline__ int blk_rank(bool act, int* cnt, int& r_out){
    unsigned long long mask = __ballot(act);
    int lane = threadIdx.x & 63, wid = threadIdx.x >> 6;
    int wrank = __popcll(mask & ((1ull << lane) - 1));
    __shared__ int ws[4];
    __shared__ int blkbase;
    if (lane == 0) ws[wid] = __popcll(mask);
    __syncthreads();
    if (threadIdx.x == 0){
        int t0 = ws[0], t1 = ws[1], t2 = ws[2], t3 = ws[3];
        int tot = t0 + t1 + t2 + t3;
        blkbase = tot ? atomicAdd(cnt, tot) : 0;
        ws[0] = 0; ws[1] = t0; ws[2] = t0 + t1; ws[3] = t0 + t1 + t2;
    }
    __syncthreads();
    r_out = blkbase + ws[wid] + wrank;
    return 0;
}

// ---------------- compact level 0 ----------------
__global__ void k_compact0(const int* cntg, int* idx0, int* list0, int* cnt0){
    int c = blockIdx.x * 256 + threadIdx.x;
    bool act = (c < NCELL0) && (cntg[c] > 0);
    int r; blk_rank(act, cnt0, r);
    if (c >= NCELL0) return;
    if (act){
        idx0[c] = r;
        int z = c / HW_; int rem = c - z * HW_;
        int y = rem / W0_; int x = rem - y * W0_;
        list0[r] = (z << 16) | (y << 8) | x;
    } else idx0[c] = -1;
}

// ---------------- compact level 1/2 ----------------
__global__ void k_compact_dn(const int* idxsrc, int* idxdst, int* listdst, int* cnt,
                             int ncell){
    int c = blockIdx.x * 256 + threadIdx.x;
    bool act = false;
    int d = 0, y = 0, x = 0;
    if (c < ncell){
        d = c / HW_; int rem = c - d * HW_;
        y = rem / W0_; x = rem - y * W0_;
        #pragma unroll
        for (int j = 0; j < 3; ++j)
            act = act || (idxsrc[((2*d + j)*H0_ + y)*W0_ + x] >= 0);
    }
    int r; blk_rank(act, cnt, r);
    if (c >= ncell) return;
    if (act){
        idxdst[c] = r;
        listdst[r] = (d << 16) | (y << 8) | x;
    } else idxdst[c] = -1;
}

// ---------------- scatter fp32 features ----------------
__global__ void k_scatter(const float* vf, const int* coors, const int* cntg,
                          const int* idx0, float* feat0f){
    int u = blockIdx.x * 256 + threadIdx.x;
    if (u >= NV_ * 32) return;
    int v = u >> 5, c4 = u & 31;
    int z = coors[v*4+1], y = coors[v*4+2], x = coors[v*4+3];
    int cell = (z*H0_ + y)*W0_ + x;
    int row = idx0[cell];
    float4 s = ((const float4*)(vf + (long)v * 128))[c4];
    float* dst = feat0f + (long)row * 128 + c4 * 4;
    if (cntg[cell] == 1){
        *(float4*)dst = s;
    } else {
        atomicAdd(dst+0, s.x); atomicAdd(dst+1, s.y);
        atomicAdd(dst+2, s.z); atomicAdd(dst+3, s.w);
    }
}

// ---------------- fp32 -> fp16 convert (8 per thread; exact for bf16-rounded values) ----------------
__global__ void k_convert(const float* f, short* b, const int* cntp){
    int n8 = cntp[0] * 16;
    int i = blockIdx.x * 256 + threadIdx.x;
    if (i >= n8) return;
    float4 a = ((const float4*)f)[i*2], c = ((const float4*)f)[i*2+1];
    short o[8] = { f2h(a.x), f2h(a.y), f2h(a.z), f2h(a.w),
                   f2h(c.x), f2h(c.y), f2h(c.z), f2h(c.w) };
    ((int4*)b)[i] = *(int4*)o;
}

// ---------------- transposed 27-tap neighbor tables: nbrT[j*cap + site] ----------------
__global__ void k_nbr27(const int* list0, const int* list1,
                        const int* idx0, const int* idx1,
                        int* nbr0T, int* nbr1T, const int* counters){
    int lvl = blockIdx.z;
    int j = blockIdx.y;
    int site = blockIdx.x * 256 + threadIdx.x;
    int M = counters[lvl];
    if (site >= M) return;
    const int* list = lvl ? list1 : list0;
    const int* idxg = lvl ? idx1 : idx0;
    int Dd = lvl ? D1_ : D0_;
    int cap = lvl ? CAP1 : CAP0;
    int cell = list[site];
    int z = cell >> 16, y = (cell >> 8) & 255, x = cell & 255;
    int nz = z + j/9 - 1, ny = y + (j/3)%3 - 1, nx = x + j%3 - 1;
    int r = -1;
    if ((unsigned)nz < (unsigned)Dd && (unsigned)ny < H0_ && (unsigned)nx < W0_)
        r = idxg[(nz*H0_ + ny)*W0_ + nx];
    (lvl ? nbr1T : nbr0T)[j * cap + site] = r;
}

// ---------------- transposed 3-tap downsample tables ----------------
__global__ void k_nbr3(const int* list1, const int* list2,
                       const int* idx0, const int* idx1,
                       int* dnb1T, int* dnb2T, const int* counters){
    int lvl = blockIdx.z;                // 0: dn1, 1: dn2
    int j = blockIdx.y;
    int site = blockIdx.x * 256 + threadIdx.x;
    int M = counters[lvl + 1];
    if (site >= M) return;
    const int* list = lvl ? list2 : list1;
    const int* idxg = lvl ? idx1 : idx0;
    int cap = lvl ? CAP2 : CAP1;
    int cell = list[site];
    int d = cell >> 16, y = (cell >> 8) & 255, x = cell & 255;
    (lvl ? dnb2T : dnb1T)[j * cap + site] = idxg[((2*d + j)*H0_ + y)*W0_ + x];
}

// ---------------- gather-GEMM: fp16, B staged in LDS, M-tile 128 ----------------
// NCH = 32-elem K-chunks per tap (4 for 128-ch input, 2 for 64-ch).
// Per tap: B(t+1) async-staged (double buffer, 1 barrier/tap); A(t+1) register-
// prefetched; nbr 2 taps ahead; fragments via conflict-free ds_read_b128.
template<int NNBR, int NCH, bool FINAL>
__global__ __launch_bounds__(256) void k_gemm(
    const short* __restrict__ featA, const int* __restrict__ nbrT, int nstride,
    const short* __restrict__ Bs, short* __restrict__ out,
    const int* __restrict__ cntp,
    const float* __restrict__ scale, const float* __restrict__ shift,
    const int* __restrict__ list, float* __restrict__ dout)
{
    __shared__ short Blds[2][NCH*4*512];
    int M = *cntp;
    int m0 = blockIdx.x * 128;
    if (m0 >= M) return;
    int tid = threadIdx.x;
    int wave = tid >> 6, lane = tid & 63;
    int m16 = lane & 15;
    int koff = (lane >> 4) * 8;
    const int ROWS = NCH * 32;               // shorts per A row

    int row0 = m0 + wave * 16 + m16;
    int row1 = row0 + 64;
    bool ok0 = row0 < M, ok1 = row1 < M;

    floatx4 acc0[4] = {}, acc1[4] = {};
    f16x8 A0[2][NCH], A1[2][NCH];
    const f16x8 z8 = {0,0,0,0,0,0,0,0};

    // wave w stages frags w*NCH .. w*NCH+NCH-1 of tap j into buffer b
    auto stageB = [&](int j, int b){
        #pragma unroll
        for (int f = 0; f < NCH; ++f){
            int frag = wave * NCH + f;
            const short* g = Bs + (((long)j * NCH * 4 + frag) * 64 + lane) * 8;
            __builtin_amdgcn_global_load_lds((gas_t)g, (las_t)&Blds[b][frag * 512],
                                             16, 0, 0);
        }
    };
    auto loadA1 = [&](f16x8* dst, int r, int kc){
        dst[kc] = (r >= 0) ? *(const f16x8*)(featA + (long)r*ROWS + koff + kc*32) : z8;
    };

    // prologue: stage B(0), load A(0), nbr(1)
    int rc0 = ok0 ? nbrT[row0] : -1;
    int rc1 = ok1 ? nbrT[row1] : -1;
    stageB(0, 0);
    #pragma unroll
    for (int kc = 0; kc < NCH; ++kc){ loadA1(A0[0], rc0, kc); loadA1(A1[0], rc1, kc); }
    int rb0 = (NNBR > 1 && ok0) ? nbrT[nstride + row0] : -1;
    int rb1 = (NNBR > 1 && ok1) ? nbrT[nstride + row1] : -1;
    int ra0 = -1, ra1 = -1;
    __syncthreads();

    #pragma unroll
    for (int t = 0; t < NNBR; ++t){
        if (t + 1 < NNBR){
            stageB(t + 1, (t + 1) & 1);
            #pragma unroll
            for (int kc = 0; kc < NCH; ++kc){ loadA1(A0[(t+1)&1], rb0, kc); loadA1(A1[(t+1)&1], rb1, kc); }
        }
        if (t + 2 < NNBR){
            ra0 = ok0 ? nbrT[(t+2)*nstride + row0] : -1;
            ra1 = ok1 ? nbrT[(t+2)*nstride + row1] : -1;
        }
        const short* Bb = Blds[t & 1];
        #pragma unroll
        for (int kc = 0; kc < NCH; ++kc){
            f16x8 b[4];
            #pragma unroll
            for (int nt = 0; nt < 4; ++nt)
                b[nt] = *(const f16x8*)&Bb[((kc*4 + nt) * 64 + lane) * 8];
            f16x8 a0 = A0[t&1][kc], a1 = A1[t&1][kc];
            #pragma unroll
            for (int nt = 0; nt < 4; ++nt)
                acc0[nt] = __builtin_amdgcn_mfma_f32_16x16x32_f16(a0, b[nt], acc0[nt], 0, 0, 0);
            #pragma unroll
            for (int nt = 0; nt < 4; ++nt)
                acc1[nt] = __builtin_amdgcn_mfma_f32_16x16x32_f16(a1, b[nt], acc1[nt], 0, 0, 0);
        }
        rb0 = ra0; rb1 = ra1;
        __syncthreads();
    }

    // epilogue: C/D layout col = lane&15, row = (lane>>4)*4 + reg
    int n16 = lane & 15;
    #pragma unroll
    for (int rg = 0; rg < 2; ++rg){
        const floatx4* ac = rg ? acc1 : acc0;
        int mb = m0 + (wave + rg*4) * 16 + (lane >> 4) * 4;
        #pragma unroll
        for (int nt = 0; nt < 4; ++nt){
            int n = nt * 16 + n16;
            float sc = scale[n], sh = shift[n];
            #pragma unroll
            for (int r = 0; r < 4; ++r){
                int site = mb + r;
                if (site < M){
                    float y = fmaxf(ac[nt][r] * sc + sh, 0.f);
                    if (FINAL){
                        int cell = list[site];
                        int d = cell >> 16, yy = (cell >> 8) & 255, xx = cell & 255;
                        dout[((n*4 + d)*H0_ + yy)*W0_ + xx] = y;
                    } else {
                        out[(long)site*64 + n] = f2h(y);
                    }
                }
            }
        }
    }
}

extern "C" void kernel_launch(void* const* d_in, const int* in_sizes, int n_in,
                              void* d_out, int out_size, void* d_ws, size_t ws_size,
                              hipStream_t stream){
    const float* vf   = (const float*)d_in[0];
    const int*   coors= (const int*)  d_in[1];
    const float* w1   = (const float*)d_in[3];
    const float* wd1  = (const float*)d_in[4];
    const float* w2   = (const float*)d_in[5];
    const float* w3   = (const float*)d_in[6];
    const float* wd2  = (const float*)d_in[7];
    const float* bng  = (const float*)d_in[8];
    const float* bnb  = (const float*)d_in[9];
    const float* bnm  = (const float*)d_in[10];
    const float* bnv  = (const float*)d_in[11];
    float* dout = (float*)d_out;

    char* ws = (char*)d_ws;
    size_t off = 0;
    auto alloc = [&](size_t bytes)->char* {
        char* p = ws + off;
        off += (bytes + 255) & ~(size_t)255;
        return p;
    };

    int*   counters = (int*)  alloc(256);                    // [0]=cnt0 [1]=cnt1 [2]=cnt2
    int*   cntg     = (int*)  alloc((size_t)NCELL0 * 4);
    int*   idx0     = (int*)  alloc((size_t)NCELL0 * 4);
    int*   idx1     = (int*)  alloc((size_t)NCELL1 * 4);
    int*   idx2     = (int*)  alloc((size_t)NCELL2 * 4);
    int*   list0    = (int*)  alloc((size_t)CAP0 * 4);
    int*   list1    = (int*)  alloc((size_t)CAP1 * 4);
    int*   list2    = (int*)  alloc((size_t)CAP2 * 4);
    float* feat0f   = (float*)alloc((size_t)CAP0 * 128 * 4);
    short* feat0h   = (short*)alloc((size_t)CAP0 * 128 * 2);  // L1 input, 128ch fp16
    short* feat1    = (short*)alloc((size_t)CAP0 * 64 * 2);   // 64ch fp16 activations
    short* featd1   = (short*)alloc((size_t)CAP1 * 64 * 2);
    short* feat2    = (short*)alloc((size_t)CAP1 * 64 * 2);
    short* feat3    = (short*)alloc((size_t)CAP1 * 64 * 2);
    int*   nbr0T    = (int*)  alloc((size_t)CAP0 * 27 * 4);
    int*   nbr1T    = (int*)  alloc((size_t)CAP1 * 27 * 4);
    int*   dnb1T    = (int*)  alloc((size_t)CAP1 * 3 * 4);
    int*   dnb2T    = (int*)  alloc((size_t)CAP2 * 3 * 4);
    short* B1  = (short*)alloc((size_t)3456 * 64 * 2);
    short* B2  = (short*)alloc((size_t)1728 * 64 * 2);
    short* B3  = (short*)alloc((size_t)1728 * 64 * 2);
    short* Bd1 = (short*)alloc((size_t)192 * 64 * 2);
    short* Bd2 = (short*)alloc((size_t)192 * 64 * 2);
    float* bnscale = (float*)alloc(5 * 64 * 4);
    float* bnshift = (float*)alloc(5 * 64 * 4);

    // ---- zero (ws/d_out poisoned 0xAA) ----
    hipMemsetAsync(counters, 0, 256 + (size_t)NCELL0 * 4, stream);
    hipMemsetAsync(feat0f, 0, (size_t)CAP0 * 128 * 4, stream);
    hipMemsetAsync(dout, 0, (size_t)out_size * 4, stream);

    // ---- constants ----
    k_prep<<<(PREP_TOT + 255)/256, 256, 0, stream>>>(w1, w2, w3, wd1, wd2,
        B1, B2, B3, Bd1, Bd2, bng, bnb, bnm, bnv, bnscale, bnshift);

    // ---- sparse structure ----
    k_count<<<(NV_ + 255)/256, 256, 0, stream>>>(coors, cntg);
    k_compact0<<<(NCELL0 + 255)/256, 256, 0, stream>>>(cntg, idx0, list0, counters + 0);
    k_scatter<<<(NV_*32 + 255)/256, 256, 0, stream>>>(vf, coors, cntg, idx0, feat0f);
    k_convert<<<(CAP0*16 + 255)/256, 256, 0, stream>>>(feat0f, feat0h, counters + 0);
    k_compact_dn<<<(NCELL1 + 255)/256, 256, 0, stream>>>(idx0, idx1, list1, counters + 1, NCELL1);
    k_compact_dn<<<(NCELL2 + 255)/256, 256, 0, stream>>>(idx1, idx2, list2, counters + 2, NCELL2);

    dim3 g27((CAP1 + 255)/256, 27, 2);
    k_nbr27<<<g27, 256, 0, stream>>>(list0, list1, idx0, idx1, nbr0T, nbr1T, counters);
    dim3 g3((CAP2 + 255)/256, 3, 2);
    k_nbr3<<<g3, 256, 0, stream>>>(list1, list2, idx0, idx1, dnb1T, dnb2T, counters);

    // ---- the five gather-GEMMs (fp16, M-tile 128, LDS-staged B) ----
    k_gemm<27,4,false><<<(CAP0+127)/128, 256, 0, stream>>>(feat0h, nbr0T, CAP0, B1, feat1,
        counters + 0, bnscale + 0,   bnshift + 0,   nullptr, nullptr);
    k_gemm<3,2,false><<<(CAP1+127)/128, 256, 0, stream>>>(feat1, dnb1T, CAP1, Bd1, featd1,
        counters + 1, bnscale + 64,  bnshift + 64,  nullptr, nullptr);
    k_gemm<27,2,false><<<(CAP1+127)/128, 256, 0, stream>>>(featd1, nbr1T, CAP1, B2, feat2,
        counters + 1, bnscale + 128, bnshift + 128, nullptr, nullptr);
    k_gemm<27,2,false><<<(CAP1+127)/128, 256, 0, stream>>>(feat2, nbr1T, CAP1, B3, feat3,
        counters + 1, bnscale + 192, bnshift + 192, nullptr, nullptr);
    k_gemm<3,2,true><<<(CAP2+127)/128, 256, 0, stream>>>(feat3, dnb2T, CAP2, Bd2, nullptr,
        counters + 2, bnscale + 256, bnshift + 256, list2, dout);
}

// Round 12
// 317.959 us; speedup vs baseline: 2.5892x; 1.0130x over previous
//
#include <hip/hip_runtime.h>

typedef float floatx4 __attribute__((ext_vector_type(4)));
typedef _Float16 f16x8 __attribute__((ext_vector_type(8)));

#define D0_ 19
#define H0_ 200
#define W0_ 176
#define HW_ (H0_*W0_)          // 35200
#define NCELL0 (D0_*HW_)       // 668800
#define D1_ 9
#define NCELL1 (D1_*HW_)       // 316800
#define D2_ 4
#define NCELL2 (D2_*HW_)       // 140800
#define NV_ 40000
#define CAP0 40000
#define CAP1 80000
#define CAP2 140800
#define EPS_ 1e-3f

typedef __attribute__((address_space(1))) const unsigned int* gas_t;
typedef __attribute__((address_space(3))) unsigned int* las_t;

__device__ __forceinline__ short f2h(float f){
    _Float16 h = (_Float16)f;
    short s; __builtin_memcpy(&s, &h, 2); return s;
}

// ---------------- fused constant prep: BN consts + 5 weight repacks (fp16) ----------------
__device__ __forceinline__ void repack_one(const float* w, short* Bout, int i,
                                           int KCsrc, int kshift, int NSP){
    int k = i >> 6, n = i & 63;
    int j = k >> kshift;
    int ci = k & (KCsrc - 1);
    short val = f2h(w[(n * KCsrc + ci) * NSP + j]);   // exact: weights bf16-rounded
    int chunk = k >> 5, lanehi = (k >> 3) & 3, jj = k & 7;
    int nt = n >> 4, lane = lanehi * 16 + (n & 15);
    Bout[((chunk * 4 + nt) * 64 + lane) * 8 + jj] = val;
}

#define RP1 (3456*64)   // 221184
#define RP2 (1728*64)   // 110592
#define RPD (192*64)    // 12288

__global__ void k_prep(const float* w1, const float* w2, const float* w3,
                       const float* wd1, const float* wd2,
                       short* B1, short* B2, short* B3, short* Bd1, short* Bd2,
                       const float* g, const float* b, const float* m, const float* v,
                       float* scale, float* shift){
    int i = blockIdx.x * 256 + threadIdx.x;
    if (i < RP1){ repack_one(w1, B1, i, 128, 7, 27); return; }
    i -= RP1;
    if (i < RP2){ repack_one(w2, B2, i, 64, 6, 27); return; }
    i -= RP2;
    if (i < RP2){ repack_one(w3, B3, i, 64, 6, 27); return; }
    i -= RP2;
    if (i < RPD){ repack_one(wd1, Bd1, i, 64, 6, 3); return; }
    i -= RPD;
    if (i < RPD){ repack_one(wd2, Bd2, i, 64, 6, 3); return; }
    i -= RPD;
    if (i < 5*64){
        float s = g[i] / sqrtf(v[i] + EPS_);
        scale[i] = s;
        shift[i] = b[i] - m[i] * s;
    }
}
#define PREP_TOT (RP1 + 2*RP2 + 2*RPD + 5*64)

// ---------------- voxel count per cell ----------------
__global__ void k_count(const int* coors, int* cntg){
    int v = blockIdx.x * 256 + threadIdx.x;
    if (v >= NV_) return;
    int z = coors[v*4+1], y = coors[v*4+2], x = coors[v*4+3];
    atomicAdd(&cntg[(z*H0_ + y)*W0_ + x], 1);
}

// ---------------- block-aggregated row assignment: ONE atomic per block ----------------
__device__ __forceinline__ int blk_rank(bool act, int* cnt, int& r_out){
    unsigned long long mask = __ballot(act);
    int lane = threadIdx.x & 63, wid = threadIdx.x >> 6;
    int wrank = __popcll(mask & ((1ull << lane) - 1));
    __shared__ int ws[4];
    __shared__ int blkbase;
    if (lane == 0) ws[wid] = __popcll(mask);
    __syncthreads();
    if (threadIdx.x == 0){
        int t0 = ws[0], t1 = ws[1], t2 = ws[2], t3 = ws[3];
        int tot = t0 + t1 + t2 + t3;
        blkbase = tot ? atomicAdd(cnt, tot) : 0;
        ws[0] = 0; ws[1] = t0; ws[2] = t0 + t1; ws[3] = t0 + t1 + t2;
    }
    __syncthreads();
    r_out = blkbase + ws[wid] + wrank;
    return 0;
}

// ---------------- compact level 0 ----------------
__global__ void k_compact0(const int* cntg, int* idx0, int* list0, int* cnt0){
    int c = blockIdx.x * 256 + threadIdx.x;
    bool act = (c < NCELL0) && (cntg[c] > 0);
    int r; blk_rank(act, cnt0, r);
    if (c >= NCELL0) return;
    if (act){
        idx0[c] = r;
        int z = c / HW_; int rem = c - z * HW_;
        int y = rem / W0_; int x = rem - y * W0_;
        list0[r] = (z << 16) | (y << 8) | x;
    } else idx0[c] = -1;
}

// ---------------- compact level 1/2 ----------------
__global__ void k_compact_dn(const int* idxsrc, int* idxdst, int* listdst, int* cnt,
                             int ncell){
    int c = blockIdx.x * 256 + threadIdx.x;
    bool act = false;
    int d = 0, y = 0, x = 0;
    if (c < ncell){
        d = c / HW_; int rem = c - d * HW_;
        y = rem / W0_; x = rem - y * W0_;
        #pragma unroll
        for (int j = 0; j < 3; ++j)
            act = act || (idxsrc[((2*d + j)*H0_ + y)*W0_ + x] >= 0);
    }
    int r; blk_rank(act, cnt, r);
    if (c >= ncell) return;
    if (act){
        idxdst[c] = r;
        listdst[r] = (d << 16) | (y << 8) | x;
    } else idxdst[c] = -1;
}

// ---------------- scatter fp32 features ----------------
__global__ void k_scatter(const float* vf, const int* coors, const int* cntg,
                          const int* idx0, float* feat0f){
    int u = blockIdx.x * 256 + threadIdx.x;
    if (u >= NV_ * 32) return;
    int v = u >> 5, c4 = u & 31;
    int z = coors[v*4+1], y = coors[v*4+2], x = coors[v*4+3];
    int cell = (z*H0_ + y)*W0_ + x;
    int row = idx0[cell];
    float4 s = ((const float4*)(vf + (long)v * 128))[c4];
    float* dst = feat0f + (long)row * 128 + c4 * 4;
    if (cntg[cell] == 1){
        *(float4*)dst = s;
    } else {
        atomicAdd(dst+0, s.x); atomicAdd(dst+1, s.y);
        atomicAdd(dst+2, s.z); atomicAdd(dst+3, s.w);
    }
}

// ---------------- fp32 -> fp16 convert (8 per thread; exact for bf16-rounded values) ----------------
__global__ void k_convert(const float* f, short* b, const int* cntp){
    int n8 = cntp[0] * 16;
    int i = blockIdx.x * 256 + threadIdx.x;
    if (i >= n8) return;
    float4 a = ((const float4*)f)[i*2], c = ((const float4*)f)[i*2+1];
    short o[8] = { f2h(a.x), f2h(a.y), f2h(a.z), f2h(a.w),
                   f2h(c.x), f2h(c.y), f2h(c.z), f2h(c.w) };
    ((int4*)b)[i] = *(int4*)o;
}

// ---------------- fused transposed neighbor tables: nbrT[j*cap + site] ----------------
// z=0/1: 27-tap levels 0/1; z=2/3: 3-tap downsample tables
__global__ void k_nbrs(const int* list0, const int* list1, const int* list2,
                       const int* idx0, const int* idx1,
                       int* nbr0T, int* nbr1T, int* dnb1T, int* dnb2T,
                       const int* counters){
    int job = blockIdx.z;
    int j = blockIdx.y;
    int site = blockIdx.x * 256 + threadIdx.x;
    if (job < 2){
        int M = counters[job];
        if (site >= M) return;
        const int* list = job ? list1 : list0;
        const int* idxg = job ? idx1 : idx0;
        int Dd = job ? D1_ : D0_;
        int cap = job ? CAP1 : CAP0;
        int cell = list[site];
        int z = cell >> 16, y = (cell >> 8) & 255, x = cell & 255;
        int nz = z + j/9 - 1, ny = y + (j/3)%3 - 1, nx = x + j%3 - 1;
        int r = -1;
        if ((unsigned)nz < (unsigned)Dd && (unsigned)ny < H0_ && (unsigned)nx < W0_)
            r = idxg[(nz*H0_ + ny)*W0_ + nx];
        (job ? nbr1T : nbr0T)[j * cap + site] = r;
    } else {
        if (j >= 3) return;
        int lvl = job - 2;
        int M = counters[lvl + 1];
        if (site >= M) return;
        const int* list = lvl ? list2 : list1;
        const int* idxg = lvl ? idx1 : idx0;
        int cap = lvl ? CAP2 : CAP1;
        int cell = list[site];
        int d = cell >> 16, y = (cell >> 8) & 255, x = cell & 255;
        (lvl ? dnb2T : dnb1T)[j * cap + site] = idxg[((2*d + j)*H0_ + y)*W0_ + x];
    }
}

// ---------------- gather-GEMM: fp16, M-tile 64, one 16-row group per wave ----------------
// NCH = 32-elem K-chunks per tap (4 for 128-ch input, 2 for 64-ch).
// B(t+1) async-staged to LDS (double buffer, 1 barrier/tap); A(t+1) register-
// prefetched; nbr 2 taps ahead. Wave-uniform tap skip when all 16 rows null.
template<int NNBR, int NCH, bool FINAL>
__global__ __launch_bounds__(256) void k_gemm(
    const short* __restrict__ featA, const int* __restrict__ nbrT, int nstride,
    const short* __restrict__ Bs, short* __restrict__ out,
    const int* __restrict__ cntp,
    const float* __restrict__ scale, const float* __restrict__ shift,
    const int* __restrict__ list, float* __restrict__ dout)
{
    __shared__ short Blds[2][NCH*4*512];
    int M = *cntp;
    int m0 = blockIdx.x * 64;
    if (m0 >= M) return;
    int tid = threadIdx.x;
    int wave = tid >> 6, lane = tid & 63;
    int m16 = lane & 15;
    int koff = (lane >> 4) * 8;
    const int ROWS = NCH * 32;               // shorts per A row
    const int FPW = NCH;                     // frags staged per wave (NCH*4/4)

    int row = m0 + wave * 16 + m16;
    bool ok = row < M;

    floatx4 acc[4] = {};
    f16x8 A[2][NCH];
    const f16x8 z8 = {0,0,0,0,0,0,0,0};

    auto stageB = [&](int j, int b){
        #pragma unroll
        for (int f = 0; f < FPW; ++f){
            int frag = wave * FPW + f;
            const short* g = Bs + (((long)j * NCH * 4 + frag) * 64 + lane) * 8;
            __builtin_amdgcn_global_load_lds((gas_t)g, (las_t)&Blds[b][frag * 512],
                                             16, 0, 0);
        }
    };
    auto loadA1 = [&](f16x8* dst, int r, int kc){
        dst[kc] = (r >= 0) ? *(const f16x8*)(featA + (long)r*ROWS + koff + kc*32) : z8;
    };

    // prologue: stage B(0), load A(0), nbr(1)
    int rc = ok ? nbrT[row] : -1;
    stageB(0, 0);
    #pragma unroll
    for (int kc = 0; kc < NCH; ++kc) loadA1(A[0], rc, kc);
    int rb = (NNBR > 1 && ok) ? nbrT[nstride + row] : -1;
    int ra = -1;
    __syncthreads();

    #pragma unroll
    for (int t = 0; t < NNBR; ++t){
        if (t + 1 < NNBR){
            stageB(t + 1, (t + 1) & 1);
            #pragma unroll
            for (int kc = 0; kc < NCH; ++kc) loadA1(A[(t+1)&1], rb, kc);
        }
        if (t + 2 < NNBR)
            ra = ok ? nbrT[(t+2)*nstride + row] : -1;
        // wave-uniform skip: all 16 rows of this wave's group null at tap t
        if (__ballot(rc >= 0) != 0){
            const short* Bb = Blds[t & 1];
            #pragma unroll
            for (int kc = 0; kc < NCH; ++kc){
                f16x8 b[4];
                #pragma unroll
                for (int nt = 0; nt < 4; ++nt)
                    b[nt] = *(const f16x8*)&Bb[((kc*4 + nt) * 64 + lane) * 8];
                f16x8 a = A[t&1][kc];
                #pragma unroll
                for (int nt = 0; nt < 4; ++nt)
                    acc[nt] = __builtin_amdgcn_mfma_f32_16x16x32_f16(a, b[nt], acc[nt], 0, 0, 0);
            }
        }
        rc = rb; rb = ra;
        __syncthreads();
    }

    // epilogue: C/D layout col = lane&15, row = (lane>>4)*4 + reg
    int n16 = lane & 15;
    int mb = m0 + wave * 16 + (lane >> 4) * 4;
    #pragma unroll
    for (int nt = 0; nt < 4; ++nt){
        int n = nt * 16 + n16;
        float sc = scale[n], sh = shift[n];
        #pragma unroll
        for (int r = 0; r < 4; ++r){
            int site = mb + r;
            if (site < M){
                float y = fmaxf(acc[nt][r] * sc + sh, 0.f);
                if (FINAL){
                    int cell = list[site];
                    int d = cell >> 16, yy = (cell >> 8) & 255, xx = cell & 255;
                    dout[((n*4 + d)*H0_ + yy)*W0_ + xx] = y;
                } else {
                    out[(long)site*64 + n] = f2h(y);
                }
            }
        }
    }
}

extern "C" void kernel_launch(void* const* d_in, const int* in_sizes, int n_in,
                              void* d_out, int out_size, void* d_ws, size_t ws_size,
                              hipStream_t stream){
    const float* vf   = (const float*)d_in[0];
    const int*   coors= (const int*)  d_in[1];
    const float* w1   = (const float*)d_in[3];
    const float* wd1  = (const float*)d_in[4];
    const float* w2   = (const float*)d_in[5];
    const float* w3   = (const float*)d_in[6];
    const float* wd2  = (const float*)d_in[7];
    const float* bng  = (const float*)d_in[8];
    const float* bnb  = (const float*)d_in[9];
    const float* bnm  = (const float*)d_in[10];
    const float* bnv  = (const float*)d_in[11];
    float* dout = (float*)d_out;

    char* ws = (char*)d_ws;
    size_t off = 0;
    auto alloc = [&](size_t bytes)->char* {
        char* p = ws + off;
        off += (bytes + 255) & ~(size_t)255;
        return p;
    };

    int*   counters = (int*)  alloc(256);                    // [0]=cnt0 [1]=cnt1 [2]=cnt2
    int*   cntg     = (int*)  alloc((size_t)NCELL0 * 4);
    int*   idx0     = (int*)  alloc((size_t)NCELL0 * 4);
    int*   idx1     = (int*)  alloc((size_t)NCELL1 * 4);
    int*   idx2     = (int*)  alloc((size_t)NCELL2 * 4);
    int*   list0    = (int*)  alloc((size_t)CAP0 * 4);
    int*   list1    = (int*)  alloc((size_t)CAP1 * 4);
    int*   list2    = (int*)  alloc((size_t)CAP2 * 4);
    float* feat0f   = (float*)alloc((size_t)CAP0 * 128 * 4);
    short* feat0h   = (short*)alloc((size_t)CAP0 * 128 * 2);  // L1 input, 128ch fp16
    short* feat1    = (short*)alloc((size_t)CAP0 * 64 * 2);   // 64ch fp16 activations
    short* featd1   = (short*)alloc((size_t)CAP1 * 64 * 2);
    short* feat2    = (short*)alloc((size_t)CAP1 * 64 * 2);
    short* feat3    = (short*)alloc((size_t)CAP1 * 64 * 2);
    int*   nbr0T    = (int*)  alloc((size_t)CAP0 * 27 * 4);
    int*   nbr1T    = (int*)  alloc((size_t)CAP1 * 27 * 4);
    int*   dnb1T    = (int*)  alloc((size_t)CAP1 * 3 * 4);
    int*   dnb2T    = (int*)  alloc((size_t)CAP2 * 3 * 4);
    short* B1  = (short*)alloc((size_t)3456 * 64 * 2);
    short* B2  = (short*)alloc((size_t)1728 * 64 * 2);
    short* B3  = (short*)alloc((size_t)1728 * 64 * 2);
    short* Bd1 = (short*)alloc((size_t)192 * 64 * 2);
    short* Bd2 = (short*)alloc((size_t)192 * 64 * 2);
    float* bnscale = (float*)alloc(5 * 64 * 4);
    float* bnshift = (float*)alloc(5 * 64 * 4);

    // ---- zero (ws/d_out poisoned 0xAA) ----
    hipMemsetAsync(counters, 0, 256 + (size_t)NCELL0 * 4, stream);
    hipMemsetAsync(feat0f, 0, (size_t)CAP0 * 128 * 4, stream);
    hipMemsetAsync(dout, 0, (size_t)out_size * 4, stream);

    // ---- constants ----
    k_prep<<<(PREP_TOT + 255)/256, 256, 0, stream>>>(w1, w2, w3, wd1, wd2,
        B1, B2, B3, Bd1, Bd2, bng, bnb, bnm, bnv, bnscale, bnshift);

    // ---- sparse structure ----
    k_count<<<(NV_ + 255)/256, 256, 0, stream>>>(coors, cntg);
    k_compact0<<<(NCELL0 + 255)/256, 256, 0, stream>>>(cntg, idx0, list0, counters + 0);
    k_scatter<<<(NV_*32 + 255)/256, 256, 0, stream>>>(vf, coors, cntg, idx0, feat0f);
    k_convert<<<(CAP0*16 + 255)/256, 256, 0, stream>>>(feat0f, feat0h, counters + 0);
    k_compact_dn<<<(NCELL1 + 255)/256, 256, 0, stream>>>(idx0, idx1, list1, counters + 1, NCELL1);
    k_compact_dn<<<(NCELL2 + 255)/256, 256, 0, stream>>>(idx1, idx2, list2, counters + 2, NCELL2);

    dim3 gn((CAP2 + 255)/256, 27, 4);
    k_nbrs<<<gn, 256, 0, stream>>>(list0, list1, list2, idx0, idx1,
                                   nbr0T, nbr1T, dnb1T, dnb2T, counters);

    // ---- the five gather-GEMMs (fp16, M-tile 64, LDS-staged B, tap skip) ----
    k_gemm<27,4,false><<<(CAP0+63)/64, 256, 0, stream>>>(feat0h, nbr0T, CAP0, B1, feat1,
        counters + 0, bnscale + 0,   bnshift + 0,   nullptr, nullptr);
    k_gemm<3,2,false><<<(CAP1+63)/64, 256, 0, stream>>>(feat1, dnb1T, CAP1, Bd1, featd1,
        counters + 1, bnscale + 64,  bnshift + 64,  nullptr, nullptr);
    k_gemm<27,2,false><<<(CAP1+63)/64, 256, 0, stream>>>(featd1, nbr1T, CAP1, B2, feat2,
        counters + 1, bnscale + 128, bnshift + 128, nullptr, nullptr);
    k_gemm<27,2,false><<<(CAP1+63)/64, 256, 0, stream>>>(feat2, nbr1T, CAP1, B3, feat3,
        counters + 1, bnscale + 192, bnshift + 192, nullptr, nullptr);
    k_gemm<3,2,true><<<(CAP2+63)/64, 256, 0, stream>>>(feat3, dnb2T, CAP2, Bd2, nullptr,
        counters + 2, bnscale + 256, bnshift + 256, list2, dout);
}